// Round 12
// baseline (614.749 us; speedup 1.0000x reference)
//
#include <hip/hip_runtime.h>

// ---------------- problem constants ----------------
// B=8 C=64 H=96 W=320 K=50 HEAD=256 CIN3=69

// d_out offsets (floats)
constexpr int OFF_O2    = 245760;
constexpr int OFF_S2    = 737280;
constexpr int OFF_HEAD  = 1228800;
constexpr int OFF_DEPTH = 1238400;
constexpr int OFF_O3D   = 1239200;
constexpr int OFF_S3D   = 1240000;
constexpr int OFF_H3D   = 1241200;

// workspace offsets (floats)
constexpr int WS_W1T  = 0;
constexpr int WS_BNSC = 635904;
constexpr int WS_BNSH = 636928;
constexpr int WS_KEEP = 637952;
constexpr int WS_INDS = 883712;
constexpr int WS_BOX  = 884112;
constexpr int WS_XS7  = 885712;
constexpr int WS_YS7  = 888512;
constexpr int WS_FU   = 891312;
constexpr int WS_H2D  = 891712;
constexpr int WS_DNO  = 892112;
constexpr int WS_ROIF = 892912;
constexpr int WS_SIG  = WS_ROIF;
constexpr int WS_W1R  = 2245312;
constexpr int WS_WPACK2 = 2245312;
constexpr int WS_FEATH  = 2540224;
constexpr int WS_FEATL  = 10618560;
constexpr long long FAST_REQ_BYTES = 18696896LL * 4;
constexpr int WS_WPACK3 = 18696896;
constexpr int WS_A3     = 19139264;
constexpr long long FAST3_REQ_BYTES = 20694464LL * 4;

typedef __attribute__((ext_vector_type(4))) float f32x4;
typedef __attribute__((ext_vector_type(8))) _Float16 f16x8;
typedef __attribute__((ext_vector_type(4))) unsigned int u32x4;

// ---------------- weight repack + BN prep ----------------
__global__ void repack_kernel(
    const float* __restrict__ w2h, const float* __restrict__ w2o, const float* __restrict__ w2s,
    const float* __restrict__ w3d, const float* __restrict__ w3o, const float* __restrict__ w3s, const float* __restrict__ w3h,
    const float* __restrict__ g0, const float* __restrict__ be0, const float* __restrict__ m0, const float* __restrict__ v0,
    const float* __restrict__ g1, const float* __restrict__ be1, const float* __restrict__ m1, const float* __restrict__ v1,
    const float* __restrict__ g2, const float* __restrict__ be2, const float* __restrict__ m2, const float* __restrict__ v2,
    const float* __restrict__ g3, const float* __restrict__ be3, const float* __restrict__ m3, const float* __restrict__ v3,
    int skip2, int skip3, float* __restrict__ ws)
{
  int i = blockIdx.x * 256 + threadIdx.x;
  if (i < 3 * 147456) {
    if (skip2) return;
    int br = i / 147456, r = i - br * 147456, q = r >> 8, c = r & 255;
    const float* src = br == 0 ? w2h : (br == 1 ? w2o : w2s);
    ws[WS_W1R + i] = src[c * 576 + q];
  } else if (i < 3 * 147456 + 4 * 158976) {
    if (skip3) return;
    int j = i - 3 * 147456;
    int br = j / 158976, r = j - br * 158976, q = r >> 8, c = r & 255;
    const float* src = br == 0 ? w3d : (br == 1 ? w3o : (br == 2 ? w3s : w3h));
    ws[WS_W1T + j] = src[c * 621 + q];
  } else {
    int j = i - (3 * 147456 + 4 * 158976);
    if (j < 1024) {
      int br = j >> 8, c = j & 255;
      const float* g  = br == 0 ? g0  : (br == 1 ? g1  : (br == 2 ? g2  : g3));
      const float* be = br == 0 ? be0 : (br == 1 ? be1 : (br == 2 ? be2 : be3));
      const float* m  = br == 0 ? m0  : (br == 1 ? m1  : (br == 2 ? m2  : m3));
      const float* v  = br == 0 ? v0  : (br == 1 ? v1  : (br == 2 ? v2  : v3));
      float sc = g[c] * rsqrtf(v[c] + 1e-5f);
      ws[WS_BNSC + j] = sc;
      ws[WS_BNSH + j] = be[c] - m[c] * sc;
    }
  }
}

// ---------------- fast path: head2 fp16 weight pack ----------------
__global__ void wpack2_kernel(const float* __restrict__ hm_w1, const float* __restrict__ o2_w1,
                              const float* __restrict__ s2_w1, float* __restrict__ ws)
{
  int i = blockIdx.x * 256 + threadIdx.x;
  if (i >= 4 * 18 * 256 * 32) return;
  int br = i / 147456; int r = i - br * 147456;
  int c = r / 8192; int r2 = r - c * 8192;
  int n = r2 >> 5; int kk = r2 & 31;
  int kg = c * 32 + kk;
  int tap = kg >> 6, ci = kg & 63;
  const float* w1 = (br == 0) ? o2_w1 : (br == 1 ? s2_w1 : hm_w1);
  float v = w1[n * 576 + ci * 9 + tap];
  _Float16 hi = (_Float16)v;
  _Float16 valh;
  if (br == 3) valh = (_Float16)(v - (float)hi);
  else valh = hi;
  unsigned short bits = __builtin_bit_cast(unsigned short, valh);
  long long didx = (((((long long)br * 18 + c) * 16 + (n >> 4)) * 4 + (kk >> 3)) * 128) + (n & 15) * 8 + (kk & 7);
  unsigned short* dst = (unsigned short*)(ws + WS_WPACK2);
  dst[didx] = bits;
}

// ---------------- fast3: head3 fp16 weight pack ----------------
__global__ void wpack3_kernel(const float* __restrict__ w3d, const float* __restrict__ w3o,
                              const float* __restrict__ w3s, const float* __restrict__ w3h,
                              float* __restrict__ ws)
{
  int i = blockIdx.x * 256 + threadIdx.x;
  if (i >= 4 * 27 * 256 * 32) return;
  int br = i / 221184; int r = i - br * 221184;
  int s = r / 8192; int r2 = r - s * 8192;
  int n = r2 >> 5; int kk = r2 & 31;
  int tap = s / 3; int cc = s - tap * 3;
  int ch = cc * 32 + kk;
  const float* w1 = br == 0 ? w3d : (br == 1 ? w3o : (br == 2 ? w3s : w3h));
  float v = (ch < 69) ? w1[n * 621 + ch * 9 + tap] : 0.f;
  unsigned short bits = __builtin_bit_cast(unsigned short, (_Float16)v);
  long long didx = (((((long long)br * 27 + s) * 16 + (n >> 4)) * 4 + (kk >> 3)) * 128) + (n & 15) * 8 + (kk & 7);
  ((unsigned short*)(ws + WS_WPACK3))[didx] = bits;
}

// ---------------- fast path: zero pad borders of featH/featL ----------------
__global__ void pad_zero_kernel(float* __restrict__ ws)
{
  int i = blockIdx.x * 256 + threadIdx.x;
  if (i >= 428032) return;
  int arr = i / 214016; int r = i - arr * 214016;
  int px = r >> 5, q = r & 31;
  int b = px / 836, pr = px - b * 836;
  int yy, xx;
  if (pr < 322) { yy = 0; xx = pr; }
  else if (pr < 644) { yy = 97; xx = pr - 322; }
  else { int t = pr - 644; yy = 1 + (t >> 1); xx = (t & 1) * 321; }
  unsigned int* dst = (unsigned int*)(ws + (arr ? WS_FEATL : WS_FEATH));
  dst[((b * 98 + yy) * 322 + xx) * 32 + q] = 0u;
}

// ---------------- fast path: transpose feat -> featH/featL ----------------
__global__ __launch_bounds__(256) void transpose_kernel(const float* __restrict__ feat, float* __restrict__ ws)
{
  __shared__ unsigned short T2[2][64 * 65];
  int bx = blockIdx.x;
  int b = bx / 480; int r = bx % 480; int y = r / 5; int x0 = (r % 5) * 64;
  int tid = threadIdx.x;
  int lx = tid & 63, grp = tid >> 6;
  #pragma unroll
  for (int it = 0; it < 16; ++it) {
    int ci = it * 4 + grp;
    float v = feat[(((b * 64 + ci) * 96 + y) * 320) + x0 + lx];
    _Float16 h = (_Float16)v;
    _Float16 l = (_Float16)(v - (float)h);
    T2[0][lx * 65 + ci] = __builtin_bit_cast(unsigned short, h);
    T2[1][lx * 65 + ci] = __builtin_bit_cast(unsigned short, l);
  }
  __syncthreads();
  unsigned int* fH = (unsigned int*)(ws + WS_FEATH);
  unsigned int* fL = (unsigned int*)(ws + WS_FEATL);
  #pragma unroll
  for (int it = 0; it < 16; ++it) {
    int unit = it * 256 + tid;
    int arr = unit >> 11; int un = unit & 2047;
    int x = un >> 5, pr = un & 31;
    unsigned int lo = T2[arr][x * 65 + pr * 2];
    unsigned int hi = T2[arr][x * 65 + pr * 2 + 1];
    unsigned int val = lo | (hi << 16);
    unsigned int* dst = arr ? fL : fH;
    dst[((b * 98 + y + 1) * 322 + (x0 + x + 1)) * 32 + pr] = val;
  }
}

// ---- transposed LDS layout: unit (row, x, j) at ((row*8 + j)*66 + x)*16 bytes ----

// ---------------- fast path: fused head2 (o2, s2, hm); 2x2 wave grid (pixel-half x N-half) ----------------
__global__ __launch_bounds__(256, 2) void head2f_kernel(
    const float* __restrict__ ws,
    const float* __restrict__ b1o, const float* __restrict__ b1s, const float* __restrict__ b1h,
    const float* __restrict__ w2o, const float* __restrict__ w2s, const float* __restrict__ w2h,
    const float* __restrict__ b2o, const float* __restrict__ b2s, const float* __restrict__ b2h,
    float* __restrict__ out, float* __restrict__ sig)
{
  __shared__ unsigned char tiles[2 * 3 * 8 * 66 * 16];  // hi @0, lo @+25344 = 50688 B
  __shared__ float red[512];
  const int tid = threadIdx.x;
  const int l = tid & 63, w = tid >> 6;
  const int wp = w & 1, wn = w >> 1;     // pixel-half, N-half
  const int bx = blockIdx.x;
  const int b = bx / 480; int r = bx % 480;
  const int y = r / 5; const int x0 = (r % 5) * 64;
  const unsigned short* fH = (const unsigned short*)(ws + WS_FEATH) + (size_t)b * (98 * 322 * 64);
  const unsigned short* fL = (const unsigned short*)(ws + WS_FEATL) + (size_t)b * (98 * 322 * 64);
  const _Float16* wpk = (const _Float16*)(ws + WS_WPACK2);

  for (int t = 0; t < 13; ++t) {
    int u = t * 256 + tid;
    if (u < 3168) {
      int arr = u >= 1584; int uu = u - arr * 1584;
      int row = uu / 528; int rem = uu - row * 528;
      int x = rem >> 3, j0 = rem & 7;
      const unsigned short* src = arr ? fL : fH;
      u32x4 v = *(const u32x4*)(src + ((y + row) * 322 + (x0 + x)) * 64 + j0 * 8);
      *(u32x4*)(tiles + arr * 25344 + ((row * 8 + j0) * 66 + x) * 16) = v;
    }
  }
  __syncthreads();

  const int l15 = l & 15, lg = l >> 4;
  const int aBase = (lg * 66 + wp * 32 + l15) * 16;

  // ---- branches 0,1: o2 / s2 (hi only) : pf=2, nf=8 ----
  #pragma unroll 1
  for (int br = 0; br < 2; ++br) {
    f32x4 acc[2][8];
    #pragma unroll
    for (int i = 0; i < 2; ++i)
      #pragma unroll
      for (int j = 0; j < 8; ++j) acc[i][j] = (f32x4)(0.f);

    const _Float16* wB = wpk + (((long long)(br * 18) * 16 + wn * 8) * 4 + lg) * 128 + l15 * 8;

    #pragma unroll
    for (int s = 0; s < 18; ++s) {
      const int tap = s >> 1, half = s & 1;
      const int ky = tap / 3, kx = tap - ky * 3;
      const int stepOff = ((ky * 8 + half * 4) * 66 + kx) * 16;
      f16x8 af[2], bf[8];
      #pragma unroll
      for (int pf = 0; pf < 2; ++pf)
        af[pf] = *(const f16x8*)(tiles + aBase + pf * 256 + stepOff);
      #pragma unroll
      for (int nf = 0; nf < 8; ++nf)
        bf[nf] = *(const f16x8*)(wB + s * 8192 + nf * 512);
      #pragma unroll
      for (int pf = 0; pf < 2; ++pf)
        #pragma unroll
        for (int nf = 0; nf < 8; ++nf)
          acc[pf][nf] = __builtin_amdgcn_mfma_f32_16x16x32_f16(af[pf], bf[nf], acc[pf][nf], 0, 0, 0);
    }

    const float* b1 = br == 0 ? b1o : b1s;
    const float* w2 = br == 0 ? w2o : w2s;
    const float* b2 = br == 0 ? b2o : b2s;
    float b1v_[8], w2v[2][8];
    #pragma unroll
    for (int nf = 0; nf < 8; ++nf) {
      int n = wn * 128 + nf * 16 + l15;
      b1v_[nf] = b1[n];
      w2v[0][nf] = w2[n];
      w2v[1][nf] = w2[256 + n];
    }
    __syncthreads();
    #pragma unroll
    for (int pf = 0; pf < 2; ++pf) {
      #pragma unroll
      for (int rr = 0; rr < 4; ++rr) {
        float s0 = 0.f, s1 = 0.f;
        #pragma unroll
        for (int nf = 0; nf < 8; ++nf) {
          float yv = acc[pf][nf][rr] + b1v_[nf];
          yv = yv > 0.f ? yv : 0.f;
          s0 = fmaf(w2v[0][nf], yv, s0);
          s1 = fmaf(w2v[1][nf], yv, s1);
        }
        #pragma unroll
        for (int m = 1; m < 16; m <<= 1) {
          s0 += __shfl_xor(s0, m);
          s1 += __shfl_xor(s1, m);
        }
        if (l15 == 0) {
          int p = wp * 32 + pf * 16 + lg * 4 + rr;
          red[(w * 2 + 0) * 64 + p] = s0;
          red[(w * 2 + 1) * 64 + p] = s1;
        }
      }
    }
    __syncthreads();
    if (tid < 128) {
      int p = tid & 63, o = tid >> 6;
      int wlo = p >> 5;   // waves (wlo, 2+wlo) cover pixel p
      float s = red[(wlo * 2 + o) * 64 + p] + red[((2 + wlo) * 2 + o) * 64 + p] + b2[o];
      int base = (br == 0) ? OFF_O2 : OFF_S2;
      out[base + ((b * 2 + o) * 96 + y) * 320 + x0 + p] = s;
    }
    __syncthreads();
  }

  // ---- branch 2: hm (hi+lo, 3 products) : pf=2, nf=8 ----
  {
    f32x4 acc[2][8];
    #pragma unroll
    for (int i = 0; i < 2; ++i)
      #pragma unroll
      for (int j = 0; j < 8; ++j) acc[i][j] = (f32x4)(0.f);

    const _Float16* wBH = wpk + (((long long)(2 * 18) * 16 + wn * 8) * 4 + lg) * 128 + l15 * 8;
    const _Float16* wBL = wpk + (((long long)(3 * 18) * 16 + wn * 8) * 4 + lg) * 128 + l15 * 8;

    #pragma unroll
    for (int s = 0; s < 18; ++s) {
      const int tap = s >> 1, half = s & 1;
      const int ky = tap / 3, kx = tap - ky * 3;
      const int stepOff = ((ky * 8 + half * 4) * 66 + kx) * 16;
      f16x8 ah[2], al[2], bh[8], bl[8];
      #pragma unroll
      for (int pf = 0; pf < 2; ++pf) {
        ah[pf] = *(const f16x8*)(tiles + aBase + pf * 256 + stepOff);
        al[pf] = *(const f16x8*)(tiles + 25344 + aBase + pf * 256 + stepOff);
      }
      #pragma unroll
      for (int nf = 0; nf < 8; ++nf) {
        bh[nf] = *(const f16x8*)(wBH + s * 8192 + nf * 512);
        bl[nf] = *(const f16x8*)(wBL + s * 8192 + nf * 512);
      }
      #pragma unroll
      for (int pf = 0; pf < 2; ++pf)
        #pragma unroll
        for (int nf = 0; nf < 8; ++nf)
          acc[pf][nf] = __builtin_amdgcn_mfma_f32_16x16x32_f16(ah[pf], bh[nf], acc[pf][nf], 0, 0, 0);
      #pragma unroll
      for (int pf = 0; pf < 2; ++pf)
        #pragma unroll
        for (int nf = 0; nf < 8; ++nf)
          acc[pf][nf] = __builtin_amdgcn_mfma_f32_16x16x32_f16(ah[pf], bl[nf], acc[pf][nf], 0, 0, 0);
      #pragma unroll
      for (int pf = 0; pf < 2; ++pf)
        #pragma unroll
        for (int nf = 0; nf < 8; ++nf)
          acc[pf][nf] = __builtin_amdgcn_mfma_f32_16x16x32_f16(al[pf], bh[nf], acc[pf][nf], 0, 0, 0);
    }

    float b1v_[8], w2v[8];
    #pragma unroll
    for (int nf = 0; nf < 8; ++nf) {
      int n = wn * 128 + nf * 16 + l15;
      b1v_[nf] = b1h[n];
      w2v[nf] = w2h[n];
    }
    __syncthreads();
    #pragma unroll
    for (int pf = 0; pf < 2; ++pf) {
      #pragma unroll
      for (int rr = 0; rr < 4; ++rr) {
        float s0 = 0.f;
        #pragma unroll
        for (int nf = 0; nf < 8; ++nf) {
          float yv = acc[pf][nf][rr] + b1v_[nf];
          yv = yv > 0.f ? yv : 0.f;
          s0 = fmaf(w2v[nf], yv, s0);
        }
        #pragma unroll
        for (int m = 1; m < 16; m <<= 1) s0 += __shfl_xor(s0, m);
        if (l15 == 0) {
          int p = wp * 32 + pf * 16 + lg * 4 + rr;
          red[w * 64 + p] = s0;
        }
      }
    }
    __syncthreads();
    if (tid < 64) {
      int wlo = tid >> 5;
      float s = red[wlo * 64 + tid] + red[(2 + wlo) * 64 + tid] + b2h[0];
      int idx = (b * 96 + y) * 320 + x0 + tid;
      out[idx] = s;
      float sg = 1.f / (1.f + expf(-s));
      sg = fminf(fmaxf(sg, 1e-4f), 1.f - 1e-4f);
      sig[idx] = sg;
    }
  }
}

// ---------------- fallback: fp32 head2 ----------------
__global__ __launch_bounds__(256) void head2_kernel(
    const float* __restrict__ feat, const float* __restrict__ ws,
    const float* __restrict__ b1h, const float* __restrict__ b1o, const float* __restrict__ b1s,
    const float* __restrict__ w2h, const float* __restrict__ w2o, const float* __restrict__ w2s,
    const float* __restrict__ b2h, const float* __restrict__ b2o, const float* __restrict__ b2s,
    float* __restrict__ out)
{
  __shared__ float xs[32 * 10 * 34];
  const int tid = threadIdx.x;
  const int tx = tid & 31, ty = tid >> 5;
  const int x0 = blockIdx.x * 32, y0 = blockIdx.y * 8, bz = blockIdx.z;
  const int px = x0 + tx, py = y0 + ty;
  const float* w1r = ws + WS_W1R;

  #pragma unroll 1
  for (int br = 0; br < 3; ++br) {
    const float* wr = w1r + br * 147456;
    const float* b1 = br == 0 ? b1h : (br == 1 ? b1o : b1s);
    const float* w2 = br == 0 ? w2h : (br == 1 ? w2o : w2s);
    const int cout = (br == 0) ? 1 : 2;
    float acc0 = 0.f, acc1 = 0.f;
    #pragma unroll 1
    for (int c0 = 0; c0 < 256; c0 += 64) {
      float part[64];
      #pragma unroll
      for (int j = 0; j < 64; ++j) part[j] = 0.f;
      #pragma unroll 1
      for (int cc = 0; cc < 2; ++cc) {
        for (int i = tid; i < 32 * 10 * 34; i += 256) {
          int ci = i / 340; int rr = i - ci * 340; int ry = rr / 34; int rx = rr - ry * 34;
          int gy = y0 + ry - 1, gx = x0 + rx - 1;
          float v = 0.f;
          if ((unsigned)gy < 96u && (unsigned)gx < 320u)
            v = feat[((bz * 64 + cc * 32 + ci) * 96 + gy) * 320 + gx];
          xs[i] = v;
        }
        __syncthreads();
        #pragma unroll 1
        for (int ci = 0; ci < 32; ++ci) {
          const float* wp = wr + ((cc * 32 + ci) * 9) * 256 + c0;
          const float* xb = &xs[ci * 340 + ty * 34 + tx];
          #pragma unroll
          for (int k = 0; k < 9; ++k) {
            float xv = xb[(k / 3) * 34 + (k % 3)];
            const float* wk = wp + k * 256;
            #pragma unroll
            for (int j = 0; j < 64; ++j) part[j] = fmaf(wk[j], xv, part[j]);
          }
        }
        __syncthreads();
      }
      #pragma unroll
      for (int j = 0; j < 64; ++j) {
        float yv = part[j] + b1[c0 + j];
        yv = yv > 0.f ? yv : 0.f;
        acc0 = fmaf(w2[c0 + j], yv, acc0);
        if (cout > 1) acc1 = fmaf(w2[256 + c0 + j], yv, acc1);
      }
    }
    if (br == 0) {
      out[(bz * 96 + py) * 320 + px] = acc0 + b2h[0];
    } else if (br == 1) {
      out[OFF_O2 + ((bz * 2 + 0) * 96 + py) * 320 + px] = acc0 + b2o[0];
      out[OFF_O2 + ((bz * 2 + 1) * 96 + py) * 320 + px] = acc1 + b2o[1];
    } else {
      out[OFF_S2 + ((bz * 2 + 0) * 96 + py) * 320 + px] = acc0 + b2s[0];
      out[OFF_S2 + ((bz * 2 + 1) * 96 + py) * 320 + px] = acc1 + b2s[1];
    }
  }
}

// ---------------- NMS ----------------
__global__ void nms_sig_kernel(const float* __restrict__ out, float* __restrict__ sig)
{
  int i = blockIdx.x * 256 + threadIdx.x;
  if (i >= 8 * 30720) return;
  float s = 1.f / (1.f + expf(-out[i]));
  s = s < 1e-4f ? 1e-4f : s;
  float hi = 1.f - 1e-4f;
  sig[i] = s > hi ? hi : s;
}

__global__ void nms_max_kernel(const float* __restrict__ sig, float* __restrict__ keep)
{
  int i = blockIdx.x * 256 + threadIdx.x;
  if (i >= 8 * 30720) return;
  int b = i / 30720; int r = i - b * 30720; int y = r / 320; int x = r - y * 320;
  const float* sb = sig + b * 30720;
  float v = sb[y * 320 + x];
  float m = v;
  for (int dy = -1; dy <= 1; ++dy)
    for (int dx = -1; dx <= 1; ++dx) {
      int yy = y + dy, xx = x + dx;
      if (yy >= 0 && yy < 96 && xx >= 0 && xx < 320) m = fmaxf(m, sb[yy * 320 + xx]);
    }
  keep[i] = (m == v) ? v : 0.f;
}

// ---------------- per-batch top-50 (wave-shuffle argmax) ----------------
__global__ __launch_bounds__(256) void topk_kernel(float* ws)
{
  constexpr int CAP = 6144;
  __shared__ float cv[CAP];
  __shared__ int   cix[CAP];
  __shared__ int   cnt;
  __shared__ float wv_[4];
  __shared__ int   wi_[4];
  __shared__ int   wsl[4];
  int b = blockIdx.x, tid = threadIdx.x;
  int lane = tid & 63, wid = tid >> 6;
  if (tid == 0) cnt = 0;
  __syncthreads();
  const float* kb = ws + WS_KEEP + b * 30720;
  for (int i = tid; i < 30720; i += 256) {
    float v = kb[i];
    if (v > 0.f) {
      int pos = atomicAdd(&cnt, 1);
      if (pos < CAP) { cv[pos] = v; cix[pos] = i; }
    }
  }
  __syncthreads();
  int ncand = cnt < CAP ? cnt : CAP;
  int* inds = (int*)(ws + WS_INDS);
  for (int k = 0; k < 50; ++k) {
    float bv = -1.f; int bi = 0x7fffffff; int bs = -1;
    for (int i = tid; i < ncand; i += 256) {
      float v = cv[i]; int id = cix[i];
      if (v > bv || (v == bv && id < bi)) { bv = v; bi = id; bs = i; }
    }
    #pragma unroll
    for (int m = 1; m < 64; m <<= 1) {
      float ov = __shfl_xor(bv, m);
      int oi = __shfl_xor(bi, m);
      int os_ = __shfl_xor(bs, m);
      if (ov > bv || (ov == bv && oi < bi)) { bv = ov; bi = oi; bs = os_; }
    }
    if (lane == 0) { wv_[wid] = bv; wi_[wid] = bi; wsl[wid] = bs; }
    __syncthreads();
    if (tid == 0) {
      float fv = wv_[0]; int fi = wi_[0]; int fs = wsl[0];
      #pragma unroll
      for (int t = 1; t < 4; ++t) {
        if (wv_[t] > fv || (wv_[t] == fv && wi_[t] < fi)) { fv = wv_[t]; fi = wi_[t]; fs = wsl[t]; }
      }
      inds[b * 50 + k] = fi;
      if (fs >= 0) cv[fs] = -1.f;
    }
    __syncthreads();
  }
}

// ---------------- boxes + rescale + projection ----------------
__global__ void boxes_kernel(const float* __restrict__ out, const float* __restrict__ coord_ranges,
                             const float* __restrict__ calibs, float* ws)
{
  int n = blockIdx.x * 256 + threadIdx.x;
  if (n >= 400) return;
  const int* inds = (const int*)(ws + WS_INDS);
  int b = n / 50;
  int idx = inds[n];
  int iy = idx / 320, ix = idx - iy * 320;
  float o2x = out[OFF_O2 + ((b * 2 + 0) * 96 + iy) * 320 + ix];
  float o2y = out[OFF_O2 + ((b * 2 + 1) * 96 + iy) * 320 + ix];
  float sw  = out[OFF_S2 + ((b * 2 + 0) * 96 + iy) * 320 + ix];
  float sh  = out[OFF_S2 + ((b * 2 + 1) * 96 + iy) * 320 + ix];
  float cx = (float)ix + o2x, cy = (float)iy + o2y;
  float x1 = cx - sw * 0.5f, y1 = cy - sh * 0.5f, x2 = cx + sw * 0.5f, y2 = cy + sh * 0.5f;
  ws[WS_BOX + n * 4 + 0] = x1; ws[WS_BOX + n * 4 + 1] = y1;
  ws[WS_BOX + n * 4 + 2] = x2; ws[WS_BOX + n * 4 + 3] = y2;
  float cr00 = coord_ranges[b * 4 + 0], cr01 = coord_ranges[b * 4 + 1];
  float sx = coord_ranges[b * 4 + 2] - cr00, sy = coord_ranges[b * 4 + 3] - cr01;
  float x1r = x1 / 320.f * sx + cr00, y1r = y1 / 96.f * sy + cr01;
  float x2r = x2 / 320.f * sx + cr00, y2r = y2 / 96.f * sy + cr01;
  const float* cl = calibs + b * 12;
  float fu = cl[0], cu = cl[2], bx = cl[3] / (-fu);
  float fv = cl[5], cvv = cl[6], by = cl[7] / (-fv);
  float p1x = (x1r - cu) / fu + bx, p1y = (y1r - cvv) / fv + by;
  float p2x = (x2r - cu) / fu + bx, p2y = (y2r - cvv) / fv + by;
  #pragma unroll
  for (int j = 0; j < 7; ++j) {
    float t = (float)j / 6.f;
    ws[WS_XS7 + n * 7 + j] = p1x + t * (p2x - p1x);
    ws[WS_YS7 + n * 7 + j] = p1y + t * (p2y - p1y);
  }
  ws[WS_FU + n] = fu;
  ws[WS_H2D + n] = fmaxf(y2r - y1r, 1.f);
}

// ---------------- ROI-align + build roi_full (fp32) + fused fp16 A3 pack ----------------
__global__ __launch_bounds__(256) void roi_kernel(const float* __restrict__ feat, int fast3, float* ws)
{
  int n = blockIdx.x;
  int tid = threadIdx.x;
  __shared__ int   iy0[14], iy1[14], ix0[14], ix1[14];
  __shared__ float fy[14], fx[14], vy[14], vx[14];
  float bx1 = ws[WS_BOX + n * 4], by1 = ws[WS_BOX + n * 4 + 1];
  float bx2 = ws[WS_BOX + n * 4 + 2], by2 = ws[WS_BOX + n * 4 + 3];
  if (tid < 14) {
    float bh = fmaxf(by2 - by1, 1.f) / 7.f;
    float g = ((float)tid + 0.5f) * 0.5f;
    float c = by1 + g * bh;
    vy[tid] = (c >= -1.f && c <= 96.f) ? 1.f : 0.f;
    c = fminf(fmaxf(c, 0.f), 95.f);
    int i0 = (int)floorf(c);
    iy0[tid] = i0; iy1[tid] = (i0 + 1 < 95) ? i0 + 1 : 95;
    fy[tid] = c - (float)i0;
  } else if (tid < 28) {
    int t = tid - 14;
    float bw = fmaxf(bx2 - bx1, 1.f) / 7.f;
    float g = ((float)t + 0.5f) * 0.5f;
    float c = bx1 + g * bw;
    vx[t] = (c >= -1.f && c <= 320.f) ? 1.f : 0.f;
    c = fminf(fmaxf(c, 0.f), 319.f);
    int i0 = (int)floorf(c);
    ix0[t] = i0; ix1[t] = (i0 + 1 < 319) ? i0 + 1 : 319;
    fx[t] = c - (float)i0;
  }
  __syncthreads();
  int bsel = n / 50;
  const float* fbase = feat + bsel * 64 * 30720;
  float* rf = ws + WS_ROIF + n * 3381;
  for (int i = tid; i < 64 * 49; i += 256) {
    int c = i / 49, p = i - c * 49;
    int oy = p / 7, ox = p - oy * 7;
    const float* fb = fbase + c * 30720;
    float s = 0.f;
    #pragma unroll
    for (int sy2 = 0; sy2 < 2; ++sy2) {
      #pragma unroll
      for (int sx2 = 0; sx2 < 2; ++sx2) {
        int jy = oy * 2 + sy2, jx = ox * 2 + sx2;
        const float* r0 = fb + iy0[jy] * 320;
        const float* r1 = fb + iy1[jy] * 320;
        float gy = fy[jy], gx = fx[jx];
        float v00 = r0[ix0[jx]], v01 = r0[ix1[jx]], v10 = r1[ix0[jx]], v11 = r1[ix1[jx]];
        float v = v00 * (1.f - gy) * (1.f - gx) + v01 * (1.f - gy) * gx
                + v10 * gy * (1.f - gx) + v11 * gy * gx;
        s += v * vy[jy] * vx[jx];
      }
    }
    rf[c * 49 + p] = s * 0.25f;
  }
  if (tid < 5 * 49) {
    int ch = tid / 49, p = tid - ch * 49;
    int oy = p / 7, ox = p - oy * 7;
    float v;
    if (ch == 0) v = ws[WS_XS7 + n * 7 + ox];
    else if (ch == 1) v = ws[WS_YS7 + n * 7 + oy];
    else if (ch == 2) v = 1.f;
    else v = 0.f;
    rf[(64 + ch) * 49 + p] = v;
  }
  if (fast3) {
    __syncthreads();
    unsigned short* a3 = (unsigned short*)(ws + WS_A3) + (size_t)n * 7776;
    for (int t = 0; t < 31; ++t) {
      int i = t * 256 + tid;
      if (i < 7776) {
        int pr = i / 96, ch = i - pr * 96;
        int py = pr / 9, px = pr - py * 9;
        float v = 0.f;
        if (py >= 1 && py <= 7 && px >= 1 && px <= 7 && ch < 69)
          v = rf[ch * 49 + (py - 1) * 7 + (px - 1)];
        a3[i] = __builtin_bit_cast(unsigned short, (_Float16)v);
      }
    }
  }
}

// ---------------- fast3: head3 MFMA (1 roi x 1 branch per block) ----------------
__global__ __launch_bounds__(256, 2) void head3m_kernel(
    float* __restrict__ ws,
    const float* __restrict__ b1d, const float* __restrict__ b1o3, const float* __restrict__ b1s3, const float* __restrict__ b1hd,
    const float* __restrict__ w2d, const float* __restrict__ w2o3, const float* __restrict__ w2s3, const float* __restrict__ w2hd,
    const float* __restrict__ b2d, const float* __restrict__ b2o3, const float* __restrict__ b2s3, const float* __restrict__ b2hd,
    float* __restrict__ out)
{
  __shared__ unsigned char A[81 * 104 * 2];
  __shared__ float ym[256];
  const int tid = threadIdx.x;
  const int l = tid & 63, w = tid >> 6;
  const int l15 = l & 15, lg = l >> 4;
  const int n = blockIdx.x;
  const int br = blockIdx.y;
  const unsigned short* a3 = (const unsigned short*)(ws + WS_A3) + (size_t)n * 7776;
  const _Float16* wp3 = (const _Float16*)(ws + WS_WPACK3);

  #pragma unroll
  for (int t = 0; t < 4; ++t) {
    int u = t * 256 + tid;
    if (u < 972) {
      int row = u / 12, cu = u - row * 12;
      u32x4 v = *(const u32x4*)(a3 + u * 8);
      *(u32x4*)(A + (row * 104 + cu * 8) * 2) = v;
    }
  }
  __syncthreads();

  int aB[4];
  #pragma unroll
  for (int pf = 0; pf < 4; ++pf) {
    int p = pf * 16 + l15;
    int rb = (p < 49) ? ((p / 7) * 9 + (p % 7)) : 0;
    aB[pf] = rb * 208 + lg * 16;
  }

  const float* b1 = br == 0 ? b1d : (br == 1 ? b1o3 : (br == 2 ? b1s3 : b1hd));
  const float* w2 = br == 0 ? w2d : (br == 1 ? w2o3 : (br == 2 ? w2s3 : w2hd));
  const float* b2 = br == 0 ? b2d : (br == 1 ? b2o3 : (br == 2 ? b2s3 : b2hd));
  const int cout = br == 0 ? 2 : (br == 1 ? 2 : (br == 2 ? 4 : 24));

  f32x4 acc[4][4];
  #pragma unroll
  for (int i = 0; i < 4; ++i)
    #pragma unroll
    for (int j = 0; j < 4; ++j) acc[i][j] = (f32x4)(0.f);

  const _Float16* wB3 = wp3 + (((long long)(br * 27) * 16 + w * 4) * 4 + lg) * 128 + l15 * 8;

  #pragma unroll
  for (int s = 0; s < 27; ++s) {
    const int tap = s / 3, cc = s - tap * 3;
    const int ky = tap / 3, kx = tap - ky * 3;
    const int stepOff = (ky * 9 + kx) * 208 + cc * 64;
    f16x8 af[4], bf[4];
    #pragma unroll
    for (int pf = 0; pf < 4; ++pf)
      af[pf] = *(const f16x8*)(A + aB[pf] + stepOff);
    #pragma unroll
    for (int nf = 0; nf < 4; ++nf)
      bf[nf] = *(const f16x8*)(wB3 + s * 8192 + nf * 512);
    #pragma unroll
    for (int pf = 0; pf < 4; ++pf)
      #pragma unroll
      for (int nf = 0; nf < 4; ++nf)
        acc[pf][nf] = __builtin_amdgcn_mfma_f32_16x16x32_f16(af[pf], bf[nf], acc[pf][nf], 0, 0, 0);
  }

  #pragma unroll
  for (int nf = 0; nf < 4; ++nf) {
    int nn = w * 64 + nf * 16 + l15;
    float b1n = b1[nn];
    float scn = ws[WS_BNSC + br * 256 + nn];
    float shn = ws[WS_BNSH + br * 256 + nn];
    float local = 0.f;
    #pragma unroll
    for (int pf = 0; pf < 4; ++pf) {
      #pragma unroll
      for (int rr = 0; rr < 4; ++rr) {
        int p = pf * 16 + lg * 4 + rr;
        float yv = (acc[pf][nf][rr] + b1n) * scn + shn;
        yv = yv > 0.f ? yv : 0.f;
        local += (p < 49) ? yv : 0.f;
      }
    }
    local += __shfl_xor(local, 16);
    local += __shfl_xor(local, 32);
    if (lg == 0) ym[nn] = local;
  }
  __syncthreads();
  for (int o = w; o < cout; o += 4) {
    float p = 0.f;
    #pragma unroll
    for (int t = 0; t < 4; ++t) p = fmaf(w2[o * 256 + t * 64 + l], ym[t * 64 + l], p);
    p *= (1.f / 49.f);
    #pragma unroll
    for (int off = 32; off > 0; off >>= 1) p += __shfl_down(p, off);
    if (l == 0) {
      float v = p + b2[o];
      if (br == 0) ws[WS_DNO + n * 2 + o] = v;
      else if (br == 1) out[OFF_O3D + n * 2 + o] = v;
      else if (br == 2) { if (o < 3) out[OFF_S3D + n * 3 + o] = v; else out[OFF_H3D + n] = v; }
      else out[OFF_HEAD + n * 24 + o] = v;
    }
  }
}

// ---------------- fallback: fp32 head3 ----------------
__global__ __launch_bounds__(256) void head3_kernel(
    float* ws,
    const float* __restrict__ b1d, const float* __restrict__ b1o3, const float* __restrict__ b1s3, const float* __restrict__ b1hd,
    const float* __restrict__ w2d, const float* __restrict__ w2o3, const float* __restrict__ w2s3, const float* __restrict__ w2hd,
    const float* __restrict__ b2d, const float* __restrict__ b2o3, const float* __restrict__ b2s3, const float* __restrict__ b2hd,
    float* __restrict__ out)
{
  int n = blockIdx.x, br = blockIdx.y;
  int c = threadIdx.x;
  __shared__ float ym[256];
  const float* wt = ws + WS_W1T + br * 158976;
  const float* b1 = br == 0 ? b1d : (br == 1 ? b1o3 : (br == 2 ? b1s3 : b1hd));
  const float* w2 = br == 0 ? w2d : (br == 1 ? w2o3 : (br == 2 ? w2s3 : w2hd));
  const float* b2 = br == 0 ? b2d : (br == 1 ? b2o3 : (br == 2 ? b2s3 : b2hd));
  const int cout = br == 0 ? 2 : (br == 1 ? 2 : (br == 2 ? 4 : 24));
  const float* xin0 = ws + WS_ROIF + n * 3381;

  float acc[49];
  #pragma unroll
  for (int i = 0; i < 49; ++i) acc[i] = 0.f;

  #pragma unroll 1
  for (int ci = 0; ci < 69; ++ci) {
    float wv[9];
    #pragma unroll
    for (int k = 0; k < 9; ++k) wv[k] = wt[(ci * 9 + k) * 256 + c];
    const float* xin = xin0 + ci * 49;
    #pragma unroll
    for (int y = 0; y < 7; ++y) {
      float xr[9];
      xr[0] = 0.f; xr[8] = 0.f;
      #pragma unroll
      for (int q = 0; q < 7; ++q) xr[q + 1] = xin[y * 7 + q];
      #pragma unroll
      for (int ky = 0; ky < 3; ++ky) {
        int pyy = y + 1 - ky;
        if (pyy >= 0 && pyy < 7) {
          #pragma unroll
          for (int kx = 0; kx < 3; ++kx) {
            float w = wv[ky * 3 + kx];
            #pragma unroll
            for (int pxx = 0; pxx < 7; ++pxx)
              acc[pyy * 7 + pxx] = fmaf(w, xr[pxx + kx], acc[pyy * 7 + pxx]);
          }
        }
      }
    }
  }
  float b1c = b1[c];
  float sc = ws[WS_BNSC + br * 256 + c];
  float sh = ws[WS_BNSH + br * 256 + c];
  float sum = 0.f;
  #pragma unroll
  for (int i = 0; i < 49; ++i) {
    float yv = (acc[i] + b1c) * sc + sh;
    sum += yv > 0.f ? yv : 0.f;
  }
  ym[c] = sum / 49.f;
  __syncthreads();
  int lane = c & 63, wid = c >> 6;
  for (int o = wid; o < cout; o += 4) {
    float p = 0.f;
    #pragma unroll
    for (int t = 0; t < 4; ++t) p = fmaf(w2[o * 256 + t * 64 + lane], ym[t * 64 + lane], p);
    #pragma unroll
    for (int off = 32; off > 0; off >>= 1) p += __shfl_down(p, off);
    if (lane == 0) {
      float v = p + b2[o];
      if (br == 0) ws[WS_DNO + n * 2 + o] = v;
      else if (br == 1) out[OFF_O3D + n * 2 + o] = v;
      else if (br == 2) { if (o < 3) out[OFF_S3D + n * 3 + o] = v; else out[OFF_H3D + n] = v; }
      else out[OFF_HEAD + n * 24 + o] = v;
    }
  }
}

// ---------------- depth epilogue ----------------
__global__ void depth_kernel(const float* ws, const float* __restrict__ mean_size, float* __restrict__ out)
{
  int n = blockIdx.x * 256 + threadIdx.x;
  if (n >= 400) return;
  float h3d = out[OFF_H3D + n];
  float s30 = out[OFF_S3D + n * 3];
  float size0 = mean_size[0] + s30;
  float f = ws[WS_FU + n], h = ws[WS_H2D + n];
  float dgeo = size0 / h * f;
  float geo = h3d + 2.f * (logf(f) - logf(h));
  float a = ws[WS_DNO + n * 2 + 1];
  float mx = fmaxf(a, geo);
  float nls = mx + logf(expf(a - mx) + expf(geo - mx));
  float sg = 1.f / (1.f + expf(-ws[WS_DNO + n * 2]));
  out[OFF_DEPTH + n * 2] = 1.f / (sg + 1e-6f) - 1.f + dgeo;
  out[OFF_DEPTH + n * 2 + 1] = nls;
}

// ---------------- launch ----------------
extern "C" void kernel_launch(void* const* d_in, const int* in_sizes, int n_in,
                              void* d_out, int out_size, void* d_ws, size_t ws_size,
                              hipStream_t stream)
{
  const float* feat         = (const float*)d_in[0];
  const float* coord_ranges = (const float*)d_in[1];
  const float* calibs       = (const float*)d_in[2];
  const float* mean_size    = (const float*)d_in[3];
  const float* hm_w1 = (const float*)d_in[4];
  const float* hm_b1 = (const float*)d_in[5];
  const float* hm_w2 = (const float*)d_in[6];
  const float* hm_b2 = (const float*)d_in[7];
  const float* o2_w1 = (const float*)d_in[8];
  const float* o2_b1 = (const float*)d_in[9];
  const float* o2_w2 = (const float*)d_in[10];
  const float* o2_b2 = (const float*)d_in[11];
  const float* s2_w1 = (const float*)d_in[12];
  const float* s2_b1 = (const float*)d_in[13];
  const float* s2_w2 = (const float*)d_in[14];
  const float* s2_b2 = (const float*)d_in[15];
  const float* dep_w1 = (const float*)d_in[16];
  const float* dep_b1 = (const float*)d_in[17];
  const float* dep_g  = (const float*)d_in[18];
  const float* dep_be = (const float*)d_in[19];
  const float* dep_m  = (const float*)d_in[20];
  const float* dep_v  = (const float*)d_in[21];
  const float* dep_w2 = (const float*)d_in[22];
  const float* dep_b2 = (const float*)d_in[23];
  const float* o3_w1 = (const float*)d_in[24];
  const float* o3_b1 = (const float*)d_in[25];
  const float* o3_g  = (const float*)d_in[26];
  const float* o3_be = (const float*)d_in[27];
  const float* o3_m  = (const float*)d_in[28];
  const float* o3_v  = (const float*)d_in[29];
  const float* o3_w2 = (const float*)d_in[30];
  const float* o3_b2 = (const float*)d_in[31];
  const float* s3_w1 = (const float*)d_in[32];
  const float* s3_b1 = (const float*)d_in[33];
  const float* s3_g  = (const float*)d_in[34];
  const float* s3_be = (const float*)d_in[35];
  const float* s3_m  = (const float*)d_in[36];
  const float* s3_v  = (const float*)d_in[37];
  const float* s3_w2 = (const float*)d_in[38];
  const float* s3_b2 = (const float*)d_in[39];
  const float* hd_w1 = (const float*)d_in[40];
  const float* hd_b1 = (const float*)d_in[41];
  const float* hd_g  = (const float*)d_in[42];
  const float* hd_be = (const float*)d_in[43];
  const float* hd_m  = (const float*)d_in[44];
  const float* hd_v  = (const float*)d_in[45];
  const float* hd_w2 = (const float*)d_in[46];
  const float* hd_b2 = (const float*)d_in[47];

  float* out = (float*)d_out;
  float* ws  = (float*)d_ws;
  bool fast  = (long long)ws_size >= FAST_REQ_BYTES;
  bool fast3 = (long long)ws_size >= FAST3_REQ_BYTES;

  repack_kernel<<<dim3((3 * 147456 + 4 * 158976 + 1024 + 255) / 256), 256, 0, stream>>>(
      hm_w1, o2_w1, s2_w1, dep_w1, o3_w1, s3_w1, hd_w1,
      dep_g, dep_be, dep_m, dep_v, o3_g, o3_be, o3_m, o3_v,
      s3_g, s3_be, s3_m, s3_v, hd_g, hd_be, hd_m, hd_v,
      fast ? 1 : 0, fast3 ? 1 : 0, ws);

  if (fast) {
    wpack2_kernel<<<dim3((4 * 18 * 256 * 32 + 255) / 256), 256, 0, stream>>>(hm_w1, o2_w1, s2_w1, ws);
    pad_zero_kernel<<<dim3((428032 + 255) / 256), 256, 0, stream>>>(ws);
    transpose_kernel<<<dim3(3840), 256, 0, stream>>>(feat, ws);
    head2f_kernel<<<dim3(3840), 256, 0, stream>>>(ws,
        o2_b1, s2_b1, hm_b1, o2_w2, s2_w2, hm_w2, o2_b2, s2_b2, hm_b2, out, ws + WS_SIG);
  } else {
    head2_kernel<<<dim3(10, 12, 8), 256, 0, stream>>>(feat, ws,
        hm_b1, o2_b1, s2_b1, hm_w2, o2_w2, s2_w2, hm_b2, o2_b2, s2_b2, out);
    nms_sig_kernel<<<dim3(960), 256, 0, stream>>>(out, ws + WS_SIG);
  }
  if (fast3)
    wpack3_kernel<<<dim3((4 * 27 * 256 * 32 + 255) / 256), 256, 0, stream>>>(dep_w1, o3_w1, s3_w1, hd_w1, ws);

  nms_max_kernel<<<dim3(960), 256, 0, stream>>>(ws + WS_SIG, ws + WS_KEEP);
  topk_kernel<<<dim3(8), 256, 0, stream>>>(ws);
  boxes_kernel<<<dim3(2), 256, 0, stream>>>(out, coord_ranges, calibs, ws);
  roi_kernel<<<dim3(400), 256, 0, stream>>>(feat, fast3 ? 1 : 0, ws);
  if (fast3) {
    head3m_kernel<<<dim3(400, 4), 256, 0, stream>>>(ws,
        dep_b1, o3_b1, s3_b1, hd_b1, dep_w2, o3_w2, s3_w2, hd_w2,
        dep_b2, o3_b2, s3_b2, hd_b2, out);
  } else {
    head3_kernel<<<dim3(400, 4), 256, 0, stream>>>(ws,
        dep_b1, o3_b1, s3_b1, hd_b1, dep_w2, o3_w2, s3_w2, hd_w2,
        dep_b2, o3_b2, s3_b2, hd_b2, out);
  }
  depth_kernel<<<dim3(2), 256, 0, stream>>>(ws, mean_size, out);
}

// Round 13
// 563.046 us; speedup vs baseline: 1.0918x; 1.0918x over previous
//
#include <hip/hip_runtime.h>

// ---------------- problem constants ----------------
// B=8 C=64 H=96 W=320 K=50 HEAD=256 CIN3=69

// d_out offsets (floats)
constexpr int OFF_O2    = 245760;
constexpr int OFF_S2    = 737280;
constexpr int OFF_HEAD  = 1228800;
constexpr int OFF_DEPTH = 1238400;
constexpr int OFF_O3D   = 1239200;
constexpr int OFF_S3D   = 1240000;
constexpr int OFF_H3D   = 1241200;

// workspace offsets (floats)
constexpr int WS_W1T  = 0;
constexpr int WS_BNSC = 635904;
constexpr int WS_BNSH = 636928;
constexpr int WS_KEEP = 637952;
constexpr int WS_INDS = 883712;
constexpr int WS_BOX  = 884112;
constexpr int WS_XS7  = 885712;
constexpr int WS_YS7  = 888512;
constexpr int WS_FU   = 891312;
constexpr int WS_H2D  = 891712;
constexpr int WS_DNO  = 892112;
constexpr int WS_ROIF = 892912;
constexpr int WS_SIG  = WS_ROIF;
constexpr int WS_W1R  = 2245312;
constexpr int WS_WPACK2 = 2245312;
constexpr int WS_FEATH  = 2540224;
constexpr int WS_FEATL  = 10618560;
constexpr long long FAST_REQ_BYTES = 18696896LL * 4;
constexpr int WS_WPACK3 = 18696896;
constexpr int WS_A3     = 19139264;
constexpr long long FAST3_REQ_BYTES = 20694464LL * 4;

typedef __attribute__((ext_vector_type(4))) float f32x4;
typedef __attribute__((ext_vector_type(8))) _Float16 f16x8;
typedef __attribute__((ext_vector_type(4))) unsigned int u32x4;

// ---------------- weight repack + BN prep ----------------
__global__ void repack_kernel(
    const float* __restrict__ w2h, const float* __restrict__ w2o, const float* __restrict__ w2s,
    const float* __restrict__ w3d, const float* __restrict__ w3o, const float* __restrict__ w3s, const float* __restrict__ w3h,
    const float* __restrict__ g0, const float* __restrict__ be0, const float* __restrict__ m0, const float* __restrict__ v0,
    const float* __restrict__ g1, const float* __restrict__ be1, const float* __restrict__ m1, const float* __restrict__ v1,
    const float* __restrict__ g2, const float* __restrict__ be2, const float* __restrict__ m2, const float* __restrict__ v2,
    const float* __restrict__ g3, const float* __restrict__ be3, const float* __restrict__ m3, const float* __restrict__ v3,
    int skip2, int skip3, float* __restrict__ ws)
{
  int i = blockIdx.x * 256 + threadIdx.x;
  if (i < 3 * 147456) {
    if (skip2) return;
    int br = i / 147456, r = i - br * 147456, q = r >> 8, c = r & 255;
    const float* src = br == 0 ? w2h : (br == 1 ? w2o : w2s);
    ws[WS_W1R + i] = src[c * 576 + q];
  } else if (i < 3 * 147456 + 4 * 158976) {
    if (skip3) return;
    int j = i - 3 * 147456;
    int br = j / 158976, r = j - br * 158976, q = r >> 8, c = r & 255;
    const float* src = br == 0 ? w3d : (br == 1 ? w3o : (br == 2 ? w3s : w3h));
    ws[WS_W1T + j] = src[c * 621 + q];
  } else {
    int j = i - (3 * 147456 + 4 * 158976);
    if (j < 1024) {
      int br = j >> 8, c = j & 255;
      const float* g  = br == 0 ? g0  : (br == 1 ? g1  : (br == 2 ? g2  : g3));
      const float* be = br == 0 ? be0 : (br == 1 ? be1 : (br == 2 ? be2 : be3));
      const float* m  = br == 0 ? m0  : (br == 1 ? m1  : (br == 2 ? m2  : m3));
      const float* v  = br == 0 ? v0  : (br == 1 ? v1  : (br == 2 ? v2  : v3));
      float sc = g[c] * rsqrtf(v[c] + 1e-5f);
      ws[WS_BNSC + j] = sc;
      ws[WS_BNSH + j] = be[c] - m[c] * sc;
    }
  }
}

// ---------------- fast path: head2 fp16 weight pack ----------------
__global__ void wpack2_kernel(const float* __restrict__ hm_w1, const float* __restrict__ o2_w1,
                              const float* __restrict__ s2_w1, float* __restrict__ ws)
{
  int i = blockIdx.x * 256 + threadIdx.x;
  if (i >= 4 * 18 * 256 * 32) return;
  int br = i / 147456; int r = i - br * 147456;
  int c = r / 8192; int r2 = r - c * 8192;
  int n = r2 >> 5; int kk = r2 & 31;
  int kg = c * 32 + kk;
  int tap = kg >> 6, ci = kg & 63;
  const float* w1 = (br == 0) ? o2_w1 : (br == 1 ? s2_w1 : hm_w1);
  float v = w1[n * 576 + ci * 9 + tap];
  _Float16 hi = (_Float16)v;
  _Float16 valh;
  if (br == 3) valh = (_Float16)(v - (float)hi);
  else valh = hi;
  unsigned short bits = __builtin_bit_cast(unsigned short, valh);
  long long didx = (((((long long)br * 18 + c) * 16 + (n >> 4)) * 4 + (kk >> 3)) * 128) + (n & 15) * 8 + (kk & 7);
  unsigned short* dst = (unsigned short*)(ws + WS_WPACK2);
  dst[didx] = bits;
}

// ---------------- fast3: head3 fp16 weight pack ----------------
__global__ void wpack3_kernel(const float* __restrict__ w3d, const float* __restrict__ w3o,
                              const float* __restrict__ w3s, const float* __restrict__ w3h,
                              float* __restrict__ ws)
{
  int i = blockIdx.x * 256 + threadIdx.x;
  if (i >= 4 * 27 * 256 * 32) return;
  int br = i / 221184; int r = i - br * 221184;
  int s = r / 8192; int r2 = r - s * 8192;
  int n = r2 >> 5; int kk = r2 & 31;
  int tap = s / 3; int cc = s - tap * 3;
  int ch = cc * 32 + kk;
  const float* w1 = br == 0 ? w3d : (br == 1 ? w3o : (br == 2 ? w3s : w3h));
  float v = (ch < 69) ? w1[n * 621 + ch * 9 + tap] : 0.f;
  unsigned short bits = __builtin_bit_cast(unsigned short, (_Float16)v);
  long long didx = (((((long long)br * 27 + s) * 16 + (n >> 4)) * 4 + (kk >> 3)) * 128) + (n & 15) * 8 + (kk & 7);
  ((unsigned short*)(ws + WS_WPACK3))[didx] = bits;
}

// ---------------- fast path: zero pad borders of featH/featL ----------------
__global__ void pad_zero_kernel(float* __restrict__ ws)
{
  int i = blockIdx.x * 256 + threadIdx.x;
  if (i >= 428032) return;
  int arr = i / 214016; int r = i - arr * 214016;
  int px = r >> 5, q = r & 31;
  int b = px / 836, pr = px - b * 836;
  int yy, xx;
  if (pr < 322) { yy = 0; xx = pr; }
  else if (pr < 644) { yy = 97; xx = pr - 322; }
  else { int t = pr - 644; yy = 1 + (t >> 1); xx = (t & 1) * 321; }
  unsigned int* dst = (unsigned int*)(ws + (arr ? WS_FEATL : WS_FEATH));
  dst[((b * 98 + yy) * 322 + xx) * 32 + q] = 0u;
}

// ---------------- fast path: transpose feat -> featH/featL ----------------
__global__ __launch_bounds__(256) void transpose_kernel(const float* __restrict__ feat, float* __restrict__ ws)
{
  __shared__ unsigned short T2[2][64 * 65];
  int bx = blockIdx.x;
  int b = bx / 480; int r = bx % 480; int y = r / 5; int x0 = (r % 5) * 64;
  int tid = threadIdx.x;
  int lx = tid & 63, grp = tid >> 6;
  #pragma unroll
  for (int it = 0; it < 16; ++it) {
    int ci = it * 4 + grp;
    float v = feat[(((b * 64 + ci) * 96 + y) * 320) + x0 + lx];
    _Float16 h = (_Float16)v;
    _Float16 l = (_Float16)(v - (float)h);
    T2[0][lx * 65 + ci] = __builtin_bit_cast(unsigned short, h);
    T2[1][lx * 65 + ci] = __builtin_bit_cast(unsigned short, l);
  }
  __syncthreads();
  unsigned int* fH = (unsigned int*)(ws + WS_FEATH);
  unsigned int* fL = (unsigned int*)(ws + WS_FEATL);
  #pragma unroll
  for (int it = 0; it < 16; ++it) {
    int unit = it * 256 + tid;
    int arr = unit >> 11; int un = unit & 2047;
    int x = un >> 5, pr = un & 31;
    unsigned int lo = T2[arr][x * 65 + pr * 2];
    unsigned int hi = T2[arr][x * 65 + pr * 2 + 1];
    unsigned int val = lo | (hi << 16);
    unsigned int* dst = arr ? fL : fH;
    dst[((b * 98 + y + 1) * 322 + (x0 + x + 1)) * 32 + pr] = val;
  }
}

// ---- transposed LDS layout: unit (row, x, j) at ((row*8 + j)*66 + x)*16 bytes ----

// ---------------- fast path: fused head2 (o2, s2, hm); r11 structure @ 3 blocks/CU ----------------
__global__ __launch_bounds__(256, 3) void head2f_kernel(
    const float* __restrict__ ws,
    const float* __restrict__ b1o, const float* __restrict__ b1s, const float* __restrict__ b1h,
    const float* __restrict__ w2o, const float* __restrict__ w2s, const float* __restrict__ w2h,
    const float* __restrict__ b2o, const float* __restrict__ b2s, const float* __restrict__ b2h,
    float* __restrict__ out, float* __restrict__ sig)
{
  __shared__ unsigned char tiles[2 * 3 * 8 * 66 * 16];  // hi @0, lo @+25344 = 50688 B
  __shared__ float red[512];
  const int tid = threadIdx.x;
  const int l = tid & 63, w = tid >> 6;
  const int bx = blockIdx.x;
  const int b = bx / 480; int r = bx % 480;
  const int y = r / 5; const int x0 = (r % 5) * 64;
  const unsigned short* fH = (const unsigned short*)(ws + WS_FEATH) + (size_t)b * (98 * 322 * 64);
  const unsigned short* fL = (const unsigned short*)(ws + WS_FEATL) + (size_t)b * (98 * 322 * 64);
  const _Float16* wpk = (const _Float16*)(ws + WS_WPACK2);

  for (int t = 0; t < 13; ++t) {
    int u = t * 256 + tid;
    if (u < 3168) {
      int arr = u >= 1584; int uu = u - arr * 1584;
      int row = uu / 528; int rem = uu - row * 528;
      int x = rem >> 3, j0 = rem & 7;
      const unsigned short* src = arr ? fL : fH;
      u32x4 v = *(const u32x4*)(src + ((y + row) * 322 + (x0 + x)) * 64 + j0 * 8);
      *(u32x4*)(tiles + arr * 25344 + ((row * 8 + j0) * 66 + x) * 16) = v;
    }
  }
  __syncthreads();

  const int l15 = l & 15, lg = l >> 4;
  const int aBase = (lg * 66 + l15) * 16;

  // ---- branches 0,1: o2 / s2 (hi only, 1 product) ----
  #pragma unroll 1
  for (int br = 0; br < 2; ++br) {
    f32x4 acc[4][4];
    #pragma unroll
    for (int i = 0; i < 4; ++i)
      #pragma unroll
      for (int j = 0; j < 4; ++j) acc[i][j] = (f32x4)(0.f);

    const _Float16* wB = wpk + (((long long)(br * 18) * 16 + w * 4) * 4 + lg) * 128 + l15 * 8;

    #pragma unroll
    for (int s = 0; s < 18; ++s) {
      const int tap = s >> 1, half = s & 1;
      const int ky = tap / 3, kx = tap - ky * 3;
      const int stepOff = ((ky * 8 + half * 4) * 66 + kx) * 16;
      f16x8 af[4], bf[4];
      #pragma unroll
      for (int pf = 0; pf < 4; ++pf)
        af[pf] = *(const f16x8*)(tiles + aBase + pf * 256 + stepOff);
      #pragma unroll
      for (int nf = 0; nf < 4; ++nf)
        bf[nf] = *(const f16x8*)(wB + s * 8192 + nf * 512);
      #pragma unroll
      for (int pf = 0; pf < 4; ++pf)
        #pragma unroll
        for (int nf = 0; nf < 4; ++nf)
          acc[pf][nf] = __builtin_amdgcn_mfma_f32_16x16x32_f16(af[pf], bf[nf], acc[pf][nf], 0, 0, 0);
    }

    const float* b1 = br == 0 ? b1o : b1s;
    const float* w2 = br == 0 ? w2o : w2s;
    const float* b2 = br == 0 ? b2o : b2s;
    float b1v_[4], w2v[2][4];
    #pragma unroll
    for (int nf = 0; nf < 4; ++nf) {
      int n = w * 64 + nf * 16 + l15;
      b1v_[nf] = b1[n];
      w2v[0][nf] = w2[n];
      w2v[1][nf] = w2[256 + n];
    }
    __syncthreads();
    #pragma unroll
    for (int pf = 0; pf < 4; ++pf) {
      #pragma unroll
      for (int rr = 0; rr < 4; ++rr) {
        float s0 = 0.f, s1 = 0.f;
        #pragma unroll
        for (int nf = 0; nf < 4; ++nf) {
          float yv = acc[pf][nf][rr] + b1v_[nf];
          yv = yv > 0.f ? yv : 0.f;
          s0 = fmaf(w2v[0][nf], yv, s0);
          s1 = fmaf(w2v[1][nf], yv, s1);
        }
        #pragma unroll
        for (int m = 1; m < 16; m <<= 1) {
          s0 += __shfl_xor(s0, m);
          s1 += __shfl_xor(s1, m);
        }
        if (l15 == 0) {
          int p = pf * 16 + lg * 4 + rr;
          red[(w * 2 + 0) * 64 + p] = s0;
          red[(w * 2 + 1) * 64 + p] = s1;
        }
      }
    }
    __syncthreads();
    if (tid < 128) {
      int p = tid & 63, o = tid >> 6;
      float s = red[(0 * 2 + o) * 64 + p] + red[(1 * 2 + o) * 64 + p] +
                red[(2 * 2 + o) * 64 + p] + red[(3 * 2 + o) * 64 + p] + b2[o];
      int base = (br == 0) ? OFF_O2 : OFF_S2;
      out[base + ((b * 2 + o) * 96 + y) * 320 + x0 + p] = s;
    }
    __syncthreads();
  }

  // ---- branch 2: hm (hi+lo, 3 products) ----
  {
    f32x4 acc[4][4];
    #pragma unroll
    for (int i = 0; i < 4; ++i)
      #pragma unroll
      for (int j = 0; j < 4; ++j) acc[i][j] = (f32x4)(0.f);

    const _Float16* wBH = wpk + (((long long)(2 * 18) * 16 + w * 4) * 4 + lg) * 128 + l15 * 8;
    const _Float16* wBL = wpk + (((long long)(3 * 18) * 16 + w * 4) * 4 + lg) * 128 + l15 * 8;

    #pragma unroll
    for (int s = 0; s < 18; ++s) {
      const int tap = s >> 1, half = s & 1;
      const int ky = tap / 3, kx = tap - ky * 3;
      const int stepOff = ((ky * 8 + half * 4) * 66 + kx) * 16;
      f16x8 ah[4], al[4], bh[4], bl[4];
      #pragma unroll
      for (int pf = 0; pf < 4; ++pf) {
        ah[pf] = *(const f16x8*)(tiles + aBase + pf * 256 + stepOff);
        al[pf] = *(const f16x8*)(tiles + 25344 + aBase + pf * 256 + stepOff);
      }
      #pragma unroll
      for (int nf = 0; nf < 4; ++nf) {
        bh[nf] = *(const f16x8*)(wBH + s * 8192 + nf * 512);
        bl[nf] = *(const f16x8*)(wBL + s * 8192 + nf * 512);
      }
      #pragma unroll
      for (int pf = 0; pf < 4; ++pf)
        #pragma unroll
        for (int nf = 0; nf < 4; ++nf)
          acc[pf][nf] = __builtin_amdgcn_mfma_f32_16x16x32_f16(ah[pf], bh[nf], acc[pf][nf], 0, 0, 0);
      #pragma unroll
      for (int pf = 0; pf < 4; ++pf)
        #pragma unroll
        for (int nf = 0; nf < 4; ++nf)
          acc[pf][nf] = __builtin_amdgcn_mfma_f32_16x16x32_f16(ah[pf], bl[nf], acc[pf][nf], 0, 0, 0);
      #pragma unroll
      for (int pf = 0; pf < 4; ++pf)
        #pragma unroll
        for (int nf = 0; nf < 4; ++nf)
          acc[pf][nf] = __builtin_amdgcn_mfma_f32_16x16x32_f16(al[pf], bh[nf], acc[pf][nf], 0, 0, 0);
    }

    float b1v_[4], w2v[4];
    #pragma unroll
    for (int nf = 0; nf < 4; ++nf) {
      int n = w * 64 + nf * 16 + l15;
      b1v_[nf] = b1h[n];
      w2v[nf] = w2h[n];
    }
    __syncthreads();
    #pragma unroll
    for (int pf = 0; pf < 4; ++pf) {
      #pragma unroll
      for (int rr = 0; rr < 4; ++rr) {
        float s0 = 0.f;
        #pragma unroll
        for (int nf = 0; nf < 4; ++nf) {
          float yv = acc[pf][nf][rr] + b1v_[nf];
          yv = yv > 0.f ? yv : 0.f;
          s0 = fmaf(w2v[nf], yv, s0);
        }
        #pragma unroll
        for (int m = 1; m < 16; m <<= 1) s0 += __shfl_xor(s0, m);
        if (l15 == 0) red[w * 64 + pf * 16 + lg * 4 + rr] = s0;
      }
    }
    __syncthreads();
    if (tid < 64) {
      float s = red[tid] + red[64 + tid] + red[128 + tid] + red[192 + tid] + b2h[0];
      int idx = (b * 96 + y) * 320 + x0 + tid;
      out[idx] = s;
      float sg = 1.f / (1.f + expf(-s));
      sg = fminf(fmaxf(sg, 1e-4f), 1.f - 1e-4f);
      sig[idx] = sg;
    }
  }
}

// ---------------- fallback: fp32 head2 ----------------
__global__ __launch_bounds__(256) void head2_kernel(
    const float* __restrict__ feat, const float* __restrict__ ws,
    const float* __restrict__ b1h, const float* __restrict__ b1o, const float* __restrict__ b1s,
    const float* __restrict__ w2h, const float* __restrict__ w2o, const float* __restrict__ w2s,
    const float* __restrict__ b2h, const float* __restrict__ b2o, const float* __restrict__ b2s,
    float* __restrict__ out)
{
  __shared__ float xs[32 * 10 * 34];
  const int tid = threadIdx.x;
  const int tx = tid & 31, ty = tid >> 5;
  const int x0 = blockIdx.x * 32, y0 = blockIdx.y * 8, bz = blockIdx.z;
  const int px = x0 + tx, py = y0 + ty;
  const float* w1r = ws + WS_W1R;

  #pragma unroll 1
  for (int br = 0; br < 3; ++br) {
    const float* wr = w1r + br * 147456;
    const float* b1 = br == 0 ? b1h : (br == 1 ? b1o : b1s);
    const float* w2 = br == 0 ? w2h : (br == 1 ? w2o : w2s);
    const int cout = (br == 0) ? 1 : 2;
    float acc0 = 0.f, acc1 = 0.f;
    #pragma unroll 1
    for (int c0 = 0; c0 < 256; c0 += 64) {
      float part[64];
      #pragma unroll
      for (int j = 0; j < 64; ++j) part[j] = 0.f;
      #pragma unroll 1
      for (int cc = 0; cc < 2; ++cc) {
        for (int i = tid; i < 32 * 10 * 34; i += 256) {
          int ci = i / 340; int rr = i - ci * 340; int ry = rr / 34; int rx = rr - ry * 34;
          int gy = y0 + ry - 1, gx = x0 + rx - 1;
          float v = 0.f;
          if ((unsigned)gy < 96u && (unsigned)gx < 320u)
            v = feat[((bz * 64 + cc * 32 + ci) * 96 + gy) * 320 + gx];
          xs[i] = v;
        }
        __syncthreads();
        #pragma unroll 1
        for (int ci = 0; ci < 32; ++ci) {
          const float* wp = wr + ((cc * 32 + ci) * 9) * 256 + c0;
          const float* xb = &xs[ci * 340 + ty * 34 + tx];
          #pragma unroll
          for (int k = 0; k < 9; ++k) {
            float xv = xb[(k / 3) * 34 + (k % 3)];
            const float* wk = wp + k * 256;
            #pragma unroll
            for (int j = 0; j < 64; ++j) part[j] = fmaf(wk[j], xv, part[j]);
          }
        }
        __syncthreads();
      }
      #pragma unroll
      for (int j = 0; j < 64; ++j) {
        float yv = part[j] + b1[c0 + j];
        yv = yv > 0.f ? yv : 0.f;
        acc0 = fmaf(w2[c0 + j], yv, acc0);
        if (cout > 1) acc1 = fmaf(w2[256 + c0 + j], yv, acc1);
      }
    }
    if (br == 0) {
      out[(bz * 96 + py) * 320 + px] = acc0 + b2h[0];
    } else if (br == 1) {
      out[OFF_O2 + ((bz * 2 + 0) * 96 + py) * 320 + px] = acc0 + b2o[0];
      out[OFF_O2 + ((bz * 2 + 1) * 96 + py) * 320 + px] = acc1 + b2o[1];
    } else {
      out[OFF_S2 + ((bz * 2 + 0) * 96 + py) * 320 + px] = acc0 + b2s[0];
      out[OFF_S2 + ((bz * 2 + 1) * 96 + py) * 320 + px] = acc1 + b2s[1];
    }
  }
}

// ---------------- NMS ----------------
__global__ void nms_sig_kernel(const float* __restrict__ out, float* __restrict__ sig)
{
  int i = blockIdx.x * 256 + threadIdx.x;
  if (i >= 8 * 30720) return;
  float s = 1.f / (1.f + expf(-out[i]));
  s = s < 1e-4f ? 1e-4f : s;
  float hi = 1.f - 1e-4f;
  sig[i] = s > hi ? hi : s;
}

__global__ void nms_max_kernel(const float* __restrict__ sig, float* __restrict__ keep)
{
  int i = blockIdx.x * 256 + threadIdx.x;
  if (i >= 8 * 30720) return;
  int b = i / 30720; int r = i - b * 30720; int y = r / 320; int x = r - y * 320;
  const float* sb = sig + b * 30720;
  float v = sb[y * 320 + x];
  float m = v;
  for (int dy = -1; dy <= 1; ++dy)
    for (int dx = -1; dx <= 1; ++dx) {
      int yy = y + dy, xx = x + dx;
      if (yy >= 0 && yy < 96 && xx >= 0 && xx < 320) m = fmaxf(m, sb[yy * 320 + xx]);
    }
  keep[i] = (m == v) ? v : 0.f;
}

// ---------------- per-batch top-50 (wave-shuffle argmax) ----------------
__global__ __launch_bounds__(256) void topk_kernel(float* ws)
{
  constexpr int CAP = 6144;
  __shared__ float cv[CAP];
  __shared__ int   cix[CAP];
  __shared__ int   cnt;
  __shared__ float wv_[4];
  __shared__ int   wi_[4];
  __shared__ int   wsl[4];
  int b = blockIdx.x, tid = threadIdx.x;
  int lane = tid & 63, wid = tid >> 6;
  if (tid == 0) cnt = 0;
  __syncthreads();
  const float* kb = ws + WS_KEEP + b * 30720;
  for (int i = tid; i < 30720; i += 256) {
    float v = kb[i];
    if (v > 0.f) {
      int pos = atomicAdd(&cnt, 1);
      if (pos < CAP) { cv[pos] = v; cix[pos] = i; }
    }
  }
  __syncthreads();
  int ncand = cnt < CAP ? cnt : CAP;
  int* inds = (int*)(ws + WS_INDS);
  for (int k = 0; k < 50; ++k) {
    float bv = -1.f; int bi = 0x7fffffff; int bs = -1;
    for (int i = tid; i < ncand; i += 256) {
      float v = cv[i]; int id = cix[i];
      if (v > bv || (v == bv && id < bi)) { bv = v; bi = id; bs = i; }
    }
    #pragma unroll
    for (int m = 1; m < 64; m <<= 1) {
      float ov = __shfl_xor(bv, m);
      int oi = __shfl_xor(bi, m);
      int os_ = __shfl_xor(bs, m);
      if (ov > bv || (ov == bv && oi < bi)) { bv = ov; bi = oi; bs = os_; }
    }
    if (lane == 0) { wv_[wid] = bv; wi_[wid] = bi; wsl[wid] = bs; }
    __syncthreads();
    if (tid == 0) {
      float fv = wv_[0]; int fi = wi_[0]; int fs = wsl[0];
      #pragma unroll
      for (int t = 1; t < 4; ++t) {
        if (wv_[t] > fv || (wv_[t] == fv && wi_[t] < fi)) { fv = wv_[t]; fi = wi_[t]; fs = wsl[t]; }
      }
      inds[b * 50 + k] = fi;
      if (fs >= 0) cv[fs] = -1.f;
    }
    __syncthreads();
  }
}

// ---------------- boxes + rescale + projection ----------------
__global__ void boxes_kernel(const float* __restrict__ out, const float* __restrict__ coord_ranges,
                             const float* __restrict__ calibs, float* ws)
{
  int n = blockIdx.x * 256 + threadIdx.x;
  if (n >= 400) return;
  const int* inds = (const int*)(ws + WS_INDS);
  int b = n / 50;
  int idx = inds[n];
  int iy = idx / 320, ix = idx - iy * 320;
  float o2x = out[OFF_O2 + ((b * 2 + 0) * 96 + iy) * 320 + ix];
  float o2y = out[OFF_O2 + ((b * 2 + 1) * 96 + iy) * 320 + ix];
  float sw  = out[OFF_S2 + ((b * 2 + 0) * 96 + iy) * 320 + ix];
  float sh  = out[OFF_S2 + ((b * 2 + 1) * 96 + iy) * 320 + ix];
  float cx = (float)ix + o2x, cy = (float)iy + o2y;
  float x1 = cx - sw * 0.5f, y1 = cy - sh * 0.5f, x2 = cx + sw * 0.5f, y2 = cy + sh * 0.5f;
  ws[WS_BOX + n * 4 + 0] = x1; ws[WS_BOX + n * 4 + 1] = y1;
  ws[WS_BOX + n * 4 + 2] = x2; ws[WS_BOX + n * 4 + 3] = y2;
  float cr00 = coord_ranges[b * 4 + 0], cr01 = coord_ranges[b * 4 + 1];
  float sx = coord_ranges[b * 4 + 2] - cr00, sy = coord_ranges[b * 4 + 3] - cr01;
  float x1r = x1 / 320.f * sx + cr00, y1r = y1 / 96.f * sy + cr01;
  float x2r = x2 / 320.f * sx + cr00, y2r = y2 / 96.f * sy + cr01;
  const float* cl = calibs + b * 12;
  float fu = cl[0], cu = cl[2], bx = cl[3] / (-fu);
  float fv = cl[5], cvv = cl[6], by = cl[7] / (-fv);
  float p1x = (x1r - cu) / fu + bx, p1y = (y1r - cvv) / fv + by;
  float p2x = (x2r - cu) / fu + bx, p2y = (y2r - cvv) / fv + by;
  #pragma unroll
  for (int j = 0; j < 7; ++j) {
    float t = (float)j / 6.f;
    ws[WS_XS7 + n * 7 + j] = p1x + t * (p2x - p1x);
    ws[WS_YS7 + n * 7 + j] = p1y + t * (p2y - p1y);
  }
  ws[WS_FU + n] = fu;
  ws[WS_H2D + n] = fmaxf(y2r - y1r, 1.f);
}

// ---------------- ROI-align + build roi_full (fp32) + fused fp16 A3 pack ----------------
__global__ __launch_bounds__(256) void roi_kernel(const float* __restrict__ feat, int fast3, float* ws)
{
  int n = blockIdx.x;
  int tid = threadIdx.x;
  __shared__ int   iy0[14], iy1[14], ix0[14], ix1[14];
  __shared__ float fy[14], fx[14], vy[14], vx[14];
  float bx1 = ws[WS_BOX + n * 4], by1 = ws[WS_BOX + n * 4 + 1];
  float bx2 = ws[WS_BOX + n * 4 + 2], by2 = ws[WS_BOX + n * 4 + 3];
  if (tid < 14) {
    float bh = fmaxf(by2 - by1, 1.f) / 7.f;
    float g = ((float)tid + 0.5f) * 0.5f;
    float c = by1 + g * bh;
    vy[tid] = (c >= -1.f && c <= 96.f) ? 1.f : 0.f;
    c = fminf(fmaxf(c, 0.f), 95.f);
    int i0 = (int)floorf(c);
    iy0[tid] = i0; iy1[tid] = (i0 + 1 < 95) ? i0 + 1 : 95;
    fy[tid] = c - (float)i0;
  } else if (tid < 28) {
    int t = tid - 14;
    float bw = fmaxf(bx2 - bx1, 1.f) / 7.f;
    float g = ((float)t + 0.5f) * 0.5f;
    float c = bx1 + g * bw;
    vx[t] = (c >= -1.f && c <= 320.f) ? 1.f : 0.f;
    c = fminf(fmaxf(c, 0.f), 319.f);
    int i0 = (int)floorf(c);
    ix0[t] = i0; ix1[t] = (i0 + 1 < 319) ? i0 + 1 : 319;
    fx[t] = c - (float)i0;
  }
  __syncthreads();
  int bsel = n / 50;
  const float* fbase = feat + bsel * 64 * 30720;
  float* rf = ws + WS_ROIF + n * 3381;
  for (int i = tid; i < 64 * 49; i += 256) {
    int c = i / 49, p = i - c * 49;
    int oy = p / 7, ox = p - oy * 7;
    const float* fb = fbase + c * 30720;
    float s = 0.f;
    #pragma unroll
    for (int sy2 = 0; sy2 < 2; ++sy2) {
      #pragma unroll
      for (int sx2 = 0; sx2 < 2; ++sx2) {
        int jy = oy * 2 + sy2, jx = ox * 2 + sx2;
        const float* r0 = fb + iy0[jy] * 320;
        const float* r1 = fb + iy1[jy] * 320;
        float gy = fy[jy], gx = fx[jx];
        float v00 = r0[ix0[jx]], v01 = r0[ix1[jx]], v10 = r1[ix0[jx]], v11 = r1[ix1[jx]];
        float v = v00 * (1.f - gy) * (1.f - gx) + v01 * (1.f - gy) * gx
                + v10 * gy * (1.f - gx) + v11 * gy * gx;
        s += v * vy[jy] * vx[jx];
      }
    }
    rf[c * 49 + p] = s * 0.25f;
  }
  if (tid < 5 * 49) {
    int ch = tid / 49, p = tid - ch * 49;
    int oy = p / 7, ox = p - oy * 7;
    float v;
    if (ch == 0) v = ws[WS_XS7 + n * 7 + ox];
    else if (ch == 1) v = ws[WS_YS7 + n * 7 + oy];
    else if (ch == 2) v = 1.f;
    else v = 0.f;
    rf[(64 + ch) * 49 + p] = v;
  }
  if (fast3) {
    __syncthreads();
    unsigned short* a3 = (unsigned short*)(ws + WS_A3) + (size_t)n * 7776;
    for (int t = 0; t < 31; ++t) {
      int i = t * 256 + tid;
      if (i < 7776) {
        int pr = i / 96, ch = i - pr * 96;
        int py = pr / 9, px = pr - py * 9;
        float v = 0.f;
        if (py >= 1 && py <= 7 && px >= 1 && px <= 7 && ch < 69)
          v = rf[ch * 49 + (py - 1) * 7 + (px - 1)];
        a3[i] = __builtin_bit_cast(unsigned short, (_Float16)v);
      }
    }
  }
}

// ---------------- fast3: head3 MFMA (1 roi x 1 branch per block) ----------------
__global__ __launch_bounds__(256, 2) void head3m_kernel(
    float* __restrict__ ws,
    const float* __restrict__ b1d, const float* __restrict__ b1o3, const float* __restrict__ b1s3, const float* __restrict__ b1hd,
    const float* __restrict__ w2d, const float* __restrict__ w2o3, const float* __restrict__ w2s3, const float* __restrict__ w2hd,
    const float* __restrict__ b2d, const float* __restrict__ b2o3, const float* __restrict__ b2s3, const float* __restrict__ b2hd,
    float* __restrict__ out)
{
  __shared__ unsigned char A[81 * 104 * 2];
  __shared__ float ym[256];
  const int tid = threadIdx.x;
  const int l = tid & 63, w = tid >> 6;
  const int l15 = l & 15, lg = l >> 4;
  const int n = blockIdx.x;
  const int br = blockIdx.y;
  const unsigned short* a3 = (const unsigned short*)(ws + WS_A3) + (size_t)n * 7776;
  const _Float16* wp3 = (const _Float16*)(ws + WS_WPACK3);

  #pragma unroll
  for (int t = 0; t < 4; ++t) {
    int u = t * 256 + tid;
    if (u < 972) {
      int row = u / 12, cu = u - row * 12;
      u32x4 v = *(const u32x4*)(a3 + u * 8);
      *(u32x4*)(A + (row * 104 + cu * 8) * 2) = v;
    }
  }
  __syncthreads();

  int aB[4];
  #pragma unroll
  for (int pf = 0; pf < 4; ++pf) {
    int p = pf * 16 + l15;
    int rb = (p < 49) ? ((p / 7) * 9 + (p % 7)) : 0;
    aB[pf] = rb * 208 + lg * 16;
  }

  const float* b1 = br == 0 ? b1d : (br == 1 ? b1o3 : (br == 2 ? b1s3 : b1hd));
  const float* w2 = br == 0 ? w2d : (br == 1 ? w2o3 : (br == 2 ? w2s3 : w2hd));
  const float* b2 = br == 0 ? b2d : (br == 1 ? b2o3 : (br == 2 ? b2s3 : b2hd));
  const int cout = br == 0 ? 2 : (br == 1 ? 2 : (br == 2 ? 4 : 24));

  f32x4 acc[4][4];
  #pragma unroll
  for (int i = 0; i < 4; ++i)
    #pragma unroll
    for (int j = 0; j < 4; ++j) acc[i][j] = (f32x4)(0.f);

  const _Float16* wB3 = wp3 + (((long long)(br * 27) * 16 + w * 4) * 4 + lg) * 128 + l15 * 8;

  #pragma unroll
  for (int s = 0; s < 27; ++s) {
    const int tap = s / 3, cc = s - tap * 3;
    const int ky = tap / 3, kx = tap - ky * 3;
    const int stepOff = (ky * 9 + kx) * 208 + cc * 64;
    f16x8 af[4], bf[4];
    #pragma unroll
    for (int pf = 0; pf < 4; ++pf)
      af[pf] = *(const f16x8*)(A + aB[pf] + stepOff);
    #pragma unroll
    for (int nf = 0; nf < 4; ++nf)
      bf[nf] = *(const f16x8*)(wB3 + s * 8192 + nf * 512);
    #pragma unroll
    for (int pf = 0; pf < 4; ++pf)
      #pragma unroll
      for (int nf = 0; nf < 4; ++nf)
        acc[pf][nf] = __builtin_amdgcn_mfma_f32_16x16x32_f16(af[pf], bf[nf], acc[pf][nf], 0, 0, 0);
  }

  #pragma unroll
  for (int nf = 0; nf < 4; ++nf) {
    int nn = w * 64 + nf * 16 + l15;
    float b1n = b1[nn];
    float scn = ws[WS_BNSC + br * 256 + nn];
    float shn = ws[WS_BNSH + br * 256 + nn];
    float local = 0.f;
    #pragma unroll
    for (int pf = 0; pf < 4; ++pf) {
      #pragma unroll
      for (int rr = 0; rr < 4; ++rr) {
        int p = pf * 16 + lg * 4 + rr;
        float yv = (acc[pf][nf][rr] + b1n) * scn + shn;
        yv = yv > 0.f ? yv : 0.f;
        local += (p < 49) ? yv : 0.f;
      }
    }
    local += __shfl_xor(local, 16);
    local += __shfl_xor(local, 32);
    if (lg == 0) ym[nn] = local;
  }
  __syncthreads();
  for (int o = w; o < cout; o += 4) {
    float p = 0.f;
    #pragma unroll
    for (int t = 0; t < 4; ++t) p = fmaf(w2[o * 256 + t * 64 + l], ym[t * 64 + l], p);
    p *= (1.f / 49.f);
    #pragma unroll
    for (int off = 32; off > 0; off >>= 1) p += __shfl_down(p, off);
    if (l == 0) {
      float v = p + b2[o];
      if (br == 0) ws[WS_DNO + n * 2 + o] = v;
      else if (br == 1) out[OFF_O3D + n * 2 + o] = v;
      else if (br == 2) { if (o < 3) out[OFF_S3D + n * 3 + o] = v; else out[OFF_H3D + n] = v; }
      else out[OFF_HEAD + n * 24 + o] = v;
    }
  }
}

// ---------------- fallback: fp32 head3 ----------------
__global__ __launch_bounds__(256) void head3_kernel(
    float* ws,
    const float* __restrict__ b1d, const float* __restrict__ b1o3, const float* __restrict__ b1s3, const float* __restrict__ b1hd,
    const float* __restrict__ w2d, const float* __restrict__ w2o3, const float* __restrict__ w2s3, const float* __restrict__ w2hd,
    const float* __restrict__ b2d, const float* __restrict__ b2o3, const float* __restrict__ b2s3, const float* __restrict__ b2hd,
    float* __restrict__ out)
{
  int n = blockIdx.x, br = blockIdx.y;
  int c = threadIdx.x;
  __shared__ float ym[256];
  const float* wt = ws + WS_W1T + br * 158976;
  const float* b1 = br == 0 ? b1d : (br == 1 ? b1o3 : (br == 2 ? b1s3 : b1hd));
  const float* w2 = br == 0 ? w2d : (br == 1 ? w2o3 : (br == 2 ? w2s3 : w2hd));
  const float* b2 = br == 0 ? b2d : (br == 1 ? b2o3 : (br == 2 ? b2s3 : b2hd));
  const int cout = br == 0 ? 2 : (br == 1 ? 2 : (br == 2 ? 4 : 24));
  const float* xin0 = ws + WS_ROIF + n * 3381;

  float acc[49];
  #pragma unroll
  for (int i = 0; i < 49; ++i) acc[i] = 0.f;

  #pragma unroll 1
  for (int ci = 0; ci < 69; ++ci) {
    float wv[9];
    #pragma unroll
    for (int k = 0; k < 9; ++k) wv[k] = wt[(ci * 9 + k) * 256 + c];
    const float* xin = xin0 + ci * 49;
    #pragma unroll
    for (int y = 0; y < 7; ++y) {
      float xr[9];
      xr[0] = 0.f; xr[8] = 0.f;
      #pragma unroll
      for (int q = 0; q < 7; ++q) xr[q + 1] = xin[y * 7 + q];
      #pragma unroll
      for (int ky = 0; ky < 3; ++ky) {
        int pyy = y + 1 - ky;
        if (pyy >= 0 && pyy < 7) {
          #pragma unroll
          for (int kx = 0; kx < 3; ++kx) {
            float w = wv[ky * 3 + kx];
            #pragma unroll
            for (int pxx = 0; pxx < 7; ++pxx)
              acc[pyy * 7 + pxx] = fmaf(w, xr[pxx + kx], acc[pyy * 7 + pxx]);
          }
        }
      }
    }
  }
  float b1c = b1[c];
  float sc = ws[WS_BNSC + br * 256 + c];
  float sh = ws[WS_BNSH + br * 256 + c];
  float sum = 0.f;
  #pragma unroll
  for (int i = 0; i < 49; ++i) {
    float yv = (acc[i] + b1c) * sc + sh;
    sum += yv > 0.f ? yv : 0.f;
  }
  ym[c] = sum / 49.f;
  __syncthreads();
  int lane = c & 63, wid = c >> 6;
  for (int o = wid; o < cout; o += 4) {
    float p = 0.f;
    #pragma unroll
    for (int t = 0; t < 4; ++t) p = fmaf(w2[o * 256 + t * 64 + lane], ym[t * 64 + lane], p);
    #pragma unroll
    for (int off = 32; off > 0; off >>= 1) p += __shfl_down(p, off);
    if (lane == 0) {
      float v = p + b2[o];
      if (br == 0) ws[WS_DNO + n * 2 + o] = v;
      else if (br == 1) out[OFF_O3D + n * 2 + o] = v;
      else if (br == 2) { if (o < 3) out[OFF_S3D + n * 3 + o] = v; else out[OFF_H3D + n] = v; }
      else out[OFF_HEAD + n * 24 + o] = v;
    }
  }
}

// ---------------- depth epilogue ----------------
__global__ void depth_kernel(const float* ws, const float* __restrict__ mean_size, float* __restrict__ out)
{
  int n = blockIdx.x * 256 + threadIdx.x;
  if (n >= 400) return;
  float h3d = out[OFF_H3D + n];
  float s30 = out[OFF_S3D + n * 3];
  float size0 = mean_size[0] + s30;
  float f = ws[WS_FU + n], h = ws[WS_H2D + n];
  float dgeo = size0 / h * f;
  float geo = h3d + 2.f * (logf(f) - logf(h));
  float a = ws[WS_DNO + n * 2 + 1];
  float mx = fmaxf(a, geo);
  float nls = mx + logf(expf(a - mx) + expf(geo - mx));
  float sg = 1.f / (1.f + expf(-ws[WS_DNO + n * 2]));
  out[OFF_DEPTH + n * 2] = 1.f / (sg + 1e-6f) - 1.f + dgeo;
  out[OFF_DEPTH + n * 2 + 1] = nls;
}

// ---------------- launch ----------------
extern "C" void kernel_launch(void* const* d_in, const int* in_sizes, int n_in,
                              void* d_out, int out_size, void* d_ws, size_t ws_size,
                              hipStream_t stream)
{
  const float* feat         = (const float*)d_in[0];
  const float* coord_ranges = (const float*)d_in[1];
  const float* calibs       = (const float*)d_in[2];
  const float* mean_size    = (const float*)d_in[3];
  const float* hm_w1 = (const float*)d_in[4];
  const float* hm_b1 = (const float*)d_in[5];
  const float* hm_w2 = (const float*)d_in[6];
  const float* hm_b2 = (const float*)d_in[7];
  const float* o2_w1 = (const float*)d_in[8];
  const float* o2_b1 = (const float*)d_in[9];
  const float* o2_w2 = (const float*)d_in[10];
  const float* o2_b2 = (const float*)d_in[11];
  const float* s2_w1 = (const float*)d_in[12];
  const float* s2_b1 = (const float*)d_in[13];
  const float* s2_w2 = (const float*)d_in[14];
  const float* s2_b2 = (const float*)d_in[15];
  const float* dep_w1 = (const float*)d_in[16];
  const float* dep_b1 = (const float*)d_in[17];
  const float* dep_g  = (const float*)d_in[18];
  const float* dep_be = (const float*)d_in[19];
  const float* dep_m  = (const float*)d_in[20];
  const float* dep_v  = (const float*)d_in[21];
  const float* dep_w2 = (const float*)d_in[22];
  const float* dep_b2 = (const float*)d_in[23];
  const float* o3_w1 = (const float*)d_in[24];
  const float* o3_b1 = (const float*)d_in[25];
  const float* o3_g  = (const float*)d_in[26];
  const float* o3_be = (const float*)d_in[27];
  const float* o3_m  = (const float*)d_in[28];
  const float* o3_v  = (const float*)d_in[29];
  const float* o3_w2 = (const float*)d_in[30];
  const float* o3_b2 = (const float*)d_in[31];
  const float* s3_w1 = (const float*)d_in[32];
  const float* s3_b1 = (const float*)d_in[33];
  const float* s3_g  = (const float*)d_in[34];
  const float* s3_be = (const float*)d_in[35];
  const float* s3_m  = (const float*)d_in[36];
  const float* s3_v  = (const float*)d_in[37];
  const float* s3_w2 = (const float*)d_in[38];
  const float* s3_b2 = (const float*)d_in[39];
  const float* hd_w1 = (const float*)d_in[40];
  const float* hd_b1 = (const float*)d_in[41];
  const float* hd_g  = (const float*)d_in[42];
  const float* hd_be = (const float*)d_in[43];
  const float* hd_m  = (const float*)d_in[44];
  const float* hd_v  = (const float*)d_in[45];
  const float* hd_w2 = (const float*)d_in[46];
  const float* hd_b2 = (const float*)d_in[47];

  float* out = (float*)d_out;
  float* ws  = (float*)d_ws;
  bool fast  = (long long)ws_size >= FAST_REQ_BYTES;
  bool fast3 = (long long)ws_size >= FAST3_REQ_BYTES;

  repack_kernel<<<dim3((3 * 147456 + 4 * 158976 + 1024 + 255) / 256), 256, 0, stream>>>(
      hm_w1, o2_w1, s2_w1, dep_w1, o3_w1, s3_w1, hd_w1,
      dep_g, dep_be, dep_m, dep_v, o3_g, o3_be, o3_m, o3_v,
      s3_g, s3_be, s3_m, s3_v, hd_g, hd_be, hd_m, hd_v,
      fast ? 1 : 0, fast3 ? 1 : 0, ws);

  if (fast) {
    wpack2_kernel<<<dim3((4 * 18 * 256 * 32 + 255) / 256), 256, 0, stream>>>(hm_w1, o2_w1, s2_w1, ws);
    pad_zero_kernel<<<dim3((428032 + 255) / 256), 256, 0, stream>>>(ws);
    transpose_kernel<<<dim3(3840), 256, 0, stream>>>(feat, ws);
    head2f_kernel<<<dim3(3840), 256, 0, stream>>>(ws,
        o2_b1, s2_b1, hm_b1, o2_w2, s2_w2, hm_w2, o2_b2, s2_b2, hm_b2, out, ws + WS_SIG);
  } else {
    head2_kernel<<<dim3(10, 12, 8), 256, 0, stream>>>(feat, ws,
        hm_b1, o2_b1, s2_b1, hm_w2, o2_w2, s2_w2, hm_b2, o2_b2, s2_b2, out);
    nms_sig_kernel<<<dim3(960), 256, 0, stream>>>(out, ws + WS_SIG);
  }
  if (fast3)
    wpack3_kernel<<<dim3((4 * 27 * 256 * 32 + 255) / 256), 256, 0, stream>>>(dep_w1, o3_w1, s3_w1, hd_w1, ws);

  nms_max_kernel<<<dim3(960), 256, 0, stream>>>(ws + WS_SIG, ws + WS_KEEP);
  topk_kernel<<<dim3(8), 256, 0, stream>>>(ws);
  boxes_kernel<<<dim3(2), 256, 0, stream>>>(out, coord_ranges, calibs, ws);
  roi_kernel<<<dim3(400), 256, 0, stream>>>(feat, fast3 ? 1 : 0, ws);
  if (fast3) {
    head3m_kernel<<<dim3(400, 4), 256, 0, stream>>>(ws,
        dep_b1, o3_b1, s3_b1, hd_b1, dep_w2, o3_w2, s3_w2, hd_w2,
        dep_b2, o3_b2, s3_b2, hd_b2, out);
  } else {
    head3_kernel<<<dim3(400, 4), 256, 0, stream>>>(ws,
        dep_b1, o3_b1, s3_b1, hd_b1, dep_w2, o3_w2, s3_w2, hd_w2,
        dep_b2, o3_b2, s3_b2, hd_b2, out);
  }
  depth_kernel<<<dim3(2), 256, 0, stream>>>(ws, mean_size, out);
}

// Round 14
// 551.066 us; speedup vs baseline: 1.1156x; 1.0217x over previous
//
#include <hip/hip_runtime.h>

// ---------------- problem constants ----------------
// B=8 C=64 H=96 W=320 K=50 HEAD=256 CIN3=69

// d_out offsets (floats)
constexpr int OFF_O2    = 245760;
constexpr int OFF_S2    = 737280;
constexpr int OFF_HEAD  = 1228800;
constexpr int OFF_DEPTH = 1238400;
constexpr int OFF_O3D   = 1239200;
constexpr int OFF_S3D   = 1240000;
constexpr int OFF_H3D   = 1241200;

// workspace offsets (floats)
constexpr int WS_W1T  = 0;
constexpr int WS_BNSC = 635904;
constexpr int WS_BNSH = 636928;
constexpr int WS_KEEP = 637952;
constexpr int WS_INDS = 883712;
constexpr int WS_BOX  = 884112;
constexpr int WS_XS7  = 885712;
constexpr int WS_YS7  = 888512;
constexpr int WS_FU   = 891312;
constexpr int WS_H2D  = 891712;
constexpr int WS_DNO  = 892112;
constexpr int WS_ROIF = 892912;
constexpr int WS_SIG  = WS_ROIF;
constexpr int WS_W1R  = 2245312;
constexpr int WS_WPACK2 = 2245312;
constexpr int WS_FEATH  = 2540224;
constexpr int WS_FEATL  = 10618560;
constexpr long long FAST_REQ_BYTES = 18696896LL * 4;
constexpr int WS_WPACK3 = 18696896;
constexpr int WS_A3     = 19139264;
constexpr long long FAST3_REQ_BYTES = 20694464LL * 4;

typedef __attribute__((ext_vector_type(4))) float f32x4;
typedef __attribute__((ext_vector_type(8))) _Float16 f16x8;
typedef __attribute__((ext_vector_type(4))) unsigned int u32x4;

// ---------------- fallback: weight repack + BN prep ----------------
__global__ void repack_kernel(
    const float* __restrict__ w2h, const float* __restrict__ w2o, const float* __restrict__ w2s,
    const float* __restrict__ w3d, const float* __restrict__ w3o, const float* __restrict__ w3s, const float* __restrict__ w3h,
    const float* __restrict__ g0, const float* __restrict__ be0, const float* __restrict__ m0, const float* __restrict__ v0,
    const float* __restrict__ g1, const float* __restrict__ be1, const float* __restrict__ m1, const float* __restrict__ v1,
    const float* __restrict__ g2, const float* __restrict__ be2, const float* __restrict__ m2, const float* __restrict__ v2,
    const float* __restrict__ g3, const float* __restrict__ be3, const float* __restrict__ m3, const float* __restrict__ v3,
    int skip2, int skip3, float* __restrict__ ws)
{
  int i = blockIdx.x * 256 + threadIdx.x;
  if (i < 3 * 147456) {
    if (skip2) return;
    int br = i / 147456, r = i - br * 147456, q = r >> 8, c = r & 255;
    const float* src = br == 0 ? w2h : (br == 1 ? w2o : w2s);
    ws[WS_W1R + i] = src[c * 576 + q];
  } else if (i < 3 * 147456 + 4 * 158976) {
    if (skip3) return;
    int j = i - 3 * 147456;
    int br = j / 158976, r = j - br * 158976, q = r >> 8, c = r & 255;
    const float* src = br == 0 ? w3d : (br == 1 ? w3o : (br == 2 ? w3s : w3h));
    ws[WS_W1T + j] = src[c * 621 + q];
  } else {
    int j = i - (3 * 147456 + 4 * 158976);
    if (j < 1024) {
      int br = j >> 8, c = j & 255;
      const float* g  = br == 0 ? g0  : (br == 1 ? g1  : (br == 2 ? g2  : g3));
      const float* be = br == 0 ? be0 : (br == 1 ? be1 : (br == 2 ? be2 : be3));
      const float* m  = br == 0 ? m0  : (br == 1 ? m1  : (br == 2 ? m2  : m3));
      const float* v  = br == 0 ? v0  : (br == 1 ? v1  : (br == 2 ? v2  : v3));
      float sc = g[c] * rsqrtf(v[c] + 1e-5f);
      ws[WS_BNSC + j] = sc;
      ws[WS_BNSH + j] = be[c] - m[c] * sc;
    }
  }
}

// ---------------- fast path: fused prep (transpose + wpack2 + pad_zero + BN + wpack3) ----------------
// blocks: [0,3840) transpose; [3840,6144) wpack2; [6144,7816) pad_zero; [7816,7820) BN; [7820,...) wpack3
__global__ __launch_bounds__(256) void prep_kernel(
    const float* __restrict__ feat,
    const float* __restrict__ hm_w1, const float* __restrict__ o2_w1, const float* __restrict__ s2_w1,
    const float* __restrict__ w3d, const float* __restrict__ w3o, const float* __restrict__ w3s, const float* __restrict__ w3h,
    const float* __restrict__ g0, const float* __restrict__ be0, const float* __restrict__ m0, const float* __restrict__ v0,
    const float* __restrict__ g1, const float* __restrict__ be1, const float* __restrict__ m1, const float* __restrict__ v1,
    const float* __restrict__ g2, const float* __restrict__ be2, const float* __restrict__ m2, const float* __restrict__ v2,
    const float* __restrict__ g3, const float* __restrict__ be3, const float* __restrict__ m3, const float* __restrict__ v3,
    float* __restrict__ ws)
{
  __shared__ unsigned short T2[2][64 * 65];
  const int bid = blockIdx.x;
  const int tid = threadIdx.x;

  if (bid < 3840) {
    // ---- transpose feat -> featH/featL ----
    int b = bid / 480; int r = bid % 480; int y = r / 5; int x0 = (r % 5) * 64;
    int lx = tid & 63, grp = tid >> 6;
    #pragma unroll
    for (int it = 0; it < 16; ++it) {
      int ci = it * 4 + grp;
      float v = feat[(((b * 64 + ci) * 96 + y) * 320) + x0 + lx];
      _Float16 h = (_Float16)v;
      _Float16 l = (_Float16)(v - (float)h);
      T2[0][lx * 65 + ci] = __builtin_bit_cast(unsigned short, h);
      T2[1][lx * 65 + ci] = __builtin_bit_cast(unsigned short, l);
    }
    __syncthreads();
    unsigned int* fH = (unsigned int*)(ws + WS_FEATH);
    unsigned int* fL = (unsigned int*)(ws + WS_FEATL);
    #pragma unroll
    for (int it = 0; it < 16; ++it) {
      int unit = it * 256 + tid;
      int arr = unit >> 11; int un = unit & 2047;
      int x = un >> 5, pr = un & 31;
      unsigned int lo = T2[arr][x * 65 + pr * 2];
      unsigned int hi = T2[arr][x * 65 + pr * 2 + 1];
      unsigned int val = lo | (hi << 16);
      unsigned int* dst = arr ? fL : fH;
      dst[((b * 98 + y + 1) * 322 + (x0 + x + 1)) * 32 + pr] = val;
    }
  } else if (bid < 6144) {
    // ---- wpack2 ----
    int i = (bid - 3840) * 256 + tid;
    int br = i / 147456; int r = i - br * 147456;
    int c = r / 8192; int r2 = r - c * 8192;
    int n = r2 >> 5; int kk = r2 & 31;
    int kg = c * 32 + kk;
    int tap = kg >> 6, ci = kg & 63;
    const float* w1 = (br == 0) ? o2_w1 : (br == 1 ? s2_w1 : hm_w1);
    float v = w1[n * 576 + ci * 9 + tap];
    _Float16 hi = (_Float16)v;
    _Float16 valh;
    if (br == 3) valh = (_Float16)(v - (float)hi);
    else valh = hi;
    unsigned short bits = __builtin_bit_cast(unsigned short, valh);
    long long didx = (((((long long)br * 18 + c) * 16 + (n >> 4)) * 4 + (kk >> 3)) * 128) + (n & 15) * 8 + (kk & 7);
    ((unsigned short*)(ws + WS_WPACK2))[didx] = bits;
  } else if (bid < 7816) {
    // ---- pad_zero ----
    int i = (bid - 6144) * 256 + tid;
    if (i < 428032) {
      int arr = i / 214016; int r = i - arr * 214016;
      int px = r >> 5, q = r & 31;
      int b = px / 836, pr = px - b * 836;
      int yy, xx;
      if (pr < 322) { yy = 0; xx = pr; }
      else if (pr < 644) { yy = 97; xx = pr - 322; }
      else { int t = pr - 644; yy = 1 + (t >> 1); xx = (t & 1) * 321; }
      unsigned int* dst = (unsigned int*)(ws + (arr ? WS_FEATL : WS_FEATH));
      dst[((b * 98 + yy) * 322 + xx) * 32 + q] = 0u;
    }
  } else if (bid < 7820) {
    // ---- BN prep ----
    int j = (bid - 7816) * 256 + tid;
    if (j < 1024) {
      int br = j >> 8, c = j & 255;
      const float* g  = br == 0 ? g0  : (br == 1 ? g1  : (br == 2 ? g2  : g3));
      const float* be = br == 0 ? be0 : (br == 1 ? be1 : (br == 2 ? be2 : be3));
      const float* m  = br == 0 ? m0  : (br == 1 ? m1  : (br == 2 ? m2  : m3));
      const float* v  = br == 0 ? v0  : (br == 1 ? v1  : (br == 2 ? v2  : v3));
      float sc = g[c] * rsqrtf(v[c] + 1e-5f);
      ws[WS_BNSC + j] = sc;
      ws[WS_BNSH + j] = be[c] - m[c] * sc;
    }
  } else {
    // ---- wpack3 ----
    int i = (bid - 7820) * 256 + tid;
    if (i < 4 * 27 * 256 * 32) {
      int br = i / 221184; int r = i - br * 221184;
      int s = r / 8192; int r2 = r - s * 8192;
      int n = r2 >> 5; int kk = r2 & 31;
      int tap = s / 3; int cc = s - tap * 3;
      int ch = cc * 32 + kk;
      const float* w1 = br == 0 ? w3d : (br == 1 ? w3o : (br == 2 ? w3s : w3h));
      float v = (ch < 69) ? w1[n * 621 + ch * 9 + tap] : 0.f;
      unsigned short bits = __builtin_bit_cast(unsigned short, (_Float16)v);
      long long didx = (((((long long)br * 27 + s) * 16 + (n >> 4)) * 4 + (kk >> 3)) * 128) + (n & 15) * 8 + (kk & 7);
      ((unsigned short*)(ws + WS_WPACK3))[didx] = bits;
    }
  }
}

// ---- transposed LDS layout: unit (row, x, j) at ((row*8 + j)*66 + x)*16 bytes ----

// ---------------- fast path: fused head2 (o2, s2, hm) ----------------
__global__ __launch_bounds__(256, 3) void head2f_kernel(
    const float* __restrict__ ws,
    const float* __restrict__ b1o, const float* __restrict__ b1s, const float* __restrict__ b1h,
    const float* __restrict__ w2o, const float* __restrict__ w2s, const float* __restrict__ w2h,
    const float* __restrict__ b2o, const float* __restrict__ b2s, const float* __restrict__ b2h,
    float* __restrict__ out, float* __restrict__ sig)
{
  __shared__ unsigned char tiles[2 * 3 * 8 * 66 * 16];  // hi @0, lo @+25344 = 50688 B
  __shared__ float red[512];
  const int tid = threadIdx.x;
  const int l = tid & 63, w = tid >> 6;
  const int bx = blockIdx.x;
  const int b = bx / 480; int r = bx % 480;
  const int y = r / 5; const int x0 = (r % 5) * 64;
  const unsigned short* fH = (const unsigned short*)(ws + WS_FEATH) + (size_t)b * (98 * 322 * 64);
  const unsigned short* fL = (const unsigned short*)(ws + WS_FEATL) + (size_t)b * (98 * 322 * 64);
  const _Float16* wpk = (const _Float16*)(ws + WS_WPACK2);

  for (int t = 0; t < 13; ++t) {
    int u = t * 256 + tid;
    if (u < 3168) {
      int arr = u >= 1584; int uu = u - arr * 1584;
      int row = uu / 528; int rem = uu - row * 528;
      int x = rem >> 3, j0 = rem & 7;
      const unsigned short* src = arr ? fL : fH;
      u32x4 v = *(const u32x4*)(src + ((y + row) * 322 + (x0 + x)) * 64 + j0 * 8);
      *(u32x4*)(tiles + arr * 25344 + ((row * 8 + j0) * 66 + x) * 16) = v;
    }
  }
  __syncthreads();

  const int l15 = l & 15, lg = l >> 4;
  const int aBase = (lg * 66 + l15) * 16;

  // ---- branches 0,1: o2 / s2 (hi only, 1 product) ----
  #pragma unroll 1
  for (int br = 0; br < 2; ++br) {
    f32x4 acc[4][4];
    #pragma unroll
    for (int i = 0; i < 4; ++i)
      #pragma unroll
      for (int j = 0; j < 4; ++j) acc[i][j] = (f32x4)(0.f);

    const _Float16* wB = wpk + (((long long)(br * 18) * 16 + w * 4) * 4 + lg) * 128 + l15 * 8;

    #pragma unroll
    for (int s = 0; s < 18; ++s) {
      const int tap = s >> 1, half = s & 1;
      const int ky = tap / 3, kx = tap - ky * 3;
      const int stepOff = ((ky * 8 + half * 4) * 66 + kx) * 16;
      f16x8 af[4], bf[4];
      #pragma unroll
      for (int pf = 0; pf < 4; ++pf)
        af[pf] = *(const f16x8*)(tiles + aBase + pf * 256 + stepOff);
      #pragma unroll
      for (int nf = 0; nf < 4; ++nf)
        bf[nf] = *(const f16x8*)(wB + s * 8192 + nf * 512);
      #pragma unroll
      for (int pf = 0; pf < 4; ++pf)
        #pragma unroll
        for (int nf = 0; nf < 4; ++nf)
          acc[pf][nf] = __builtin_amdgcn_mfma_f32_16x16x32_f16(af[pf], bf[nf], acc[pf][nf], 0, 0, 0);
    }

    const float* b1 = br == 0 ? b1o : b1s;
    const float* w2 = br == 0 ? w2o : w2s;
    const float* b2 = br == 0 ? b2o : b2s;
    float b1v_[4], w2v[2][4];
    #pragma unroll
    for (int nf = 0; nf < 4; ++nf) {
      int n = w * 64 + nf * 16 + l15;
      b1v_[nf] = b1[n];
      w2v[0][nf] = w2[n];
      w2v[1][nf] = w2[256 + n];
    }
    __syncthreads();
    #pragma unroll
    for (int pf = 0; pf < 4; ++pf) {
      #pragma unroll
      for (int rr = 0; rr < 4; ++rr) {
        float s0 = 0.f, s1 = 0.f;
        #pragma unroll
        for (int nf = 0; nf < 4; ++nf) {
          float yv = acc[pf][nf][rr] + b1v_[nf];
          yv = yv > 0.f ? yv : 0.f;
          s0 = fmaf(w2v[0][nf], yv, s0);
          s1 = fmaf(w2v[1][nf], yv, s1);
        }
        #pragma unroll
        for (int m = 1; m < 16; m <<= 1) {
          s0 += __shfl_xor(s0, m);
          s1 += __shfl_xor(s1, m);
        }
        if (l15 == 0) {
          int p = pf * 16 + lg * 4 + rr;
          red[(w * 2 + 0) * 64 + p] = s0;
          red[(w * 2 + 1) * 64 + p] = s1;
        }
      }
    }
    __syncthreads();
    if (tid < 128) {
      int p = tid & 63, o = tid >> 6;
      float s = red[(0 * 2 + o) * 64 + p] + red[(1 * 2 + o) * 64 + p] +
                red[(2 * 2 + o) * 64 + p] + red[(3 * 2 + o) * 64 + p] + b2[o];
      int base = (br == 0) ? OFF_O2 : OFF_S2;
      out[base + ((b * 2 + o) * 96 + y) * 320 + x0 + p] = s;
    }
    __syncthreads();
  }

  // ---- branch 2: hm (hi+lo, 3 products) ----
  {
    f32x4 acc[4][4];
    #pragma unroll
    for (int i = 0; i < 4; ++i)
      #pragma unroll
      for (int j = 0; j < 4; ++j) acc[i][j] = (f32x4)(0.f);

    const _Float16* wBH = wpk + (((long long)(2 * 18) * 16 + w * 4) * 4 + lg) * 128 + l15 * 8;
    const _Float16* wBL = wpk + (((long long)(3 * 18) * 16 + w * 4) * 4 + lg) * 128 + l15 * 8;

    #pragma unroll
    for (int s = 0; s < 18; ++s) {
      const int tap = s >> 1, half = s & 1;
      const int ky = tap / 3, kx = tap - ky * 3;
      const int stepOff = ((ky * 8 + half * 4) * 66 + kx) * 16;
      f16x8 ah[4], al[4], bh[4], bl[4];
      #pragma unroll
      for (int pf = 0; pf < 4; ++pf) {
        ah[pf] = *(const f16x8*)(tiles + aBase + pf * 256 + stepOff);
        al[pf] = *(const f16x8*)(tiles + 25344 + aBase + pf * 256 + stepOff);
      }
      #pragma unroll
      for (int nf = 0; nf < 4; ++nf) {
        bh[nf] = *(const f16x8*)(wBH + s * 8192 + nf * 512);
        bl[nf] = *(const f16x8*)(wBL + s * 8192 + nf * 512);
      }
      #pragma unroll
      for (int pf = 0; pf < 4; ++pf)
        #pragma unroll
        for (int nf = 0; nf < 4; ++nf)
          acc[pf][nf] = __builtin_amdgcn_mfma_f32_16x16x32_f16(ah[pf], bh[nf], acc[pf][nf], 0, 0, 0);
      #pragma unroll
      for (int pf = 0; pf < 4; ++pf)
        #pragma unroll
        for (int nf = 0; nf < 4; ++nf)
          acc[pf][nf] = __builtin_amdgcn_mfma_f32_16x16x32_f16(ah[pf], bl[nf], acc[pf][nf], 0, 0, 0);
      #pragma unroll
      for (int pf = 0; pf < 4; ++pf)
        #pragma unroll
        for (int nf = 0; nf < 4; ++nf)
          acc[pf][nf] = __builtin_amdgcn_mfma_f32_16x16x32_f16(al[pf], bh[nf], acc[pf][nf], 0, 0, 0);
    }

    float b1v_[4], w2v[4];
    #pragma unroll
    for (int nf = 0; nf < 4; ++nf) {
      int n = w * 64 + nf * 16 + l15;
      b1v_[nf] = b1h[n];
      w2v[nf] = w2h[n];
    }
    __syncthreads();
    #pragma unroll
    for (int pf = 0; pf < 4; ++pf) {
      #pragma unroll
      for (int rr = 0; rr < 4; ++rr) {
        float s0 = 0.f;
        #pragma unroll
        for (int nf = 0; nf < 4; ++nf) {
          float yv = acc[pf][nf][rr] + b1v_[nf];
          yv = yv > 0.f ? yv : 0.f;
          s0 = fmaf(w2v[nf], yv, s0);
        }
        #pragma unroll
        for (int m = 1; m < 16; m <<= 1) s0 += __shfl_xor(s0, m);
        if (l15 == 0) red[w * 64 + pf * 16 + lg * 4 + rr] = s0;
      }
    }
    __syncthreads();
    if (tid < 64) {
      float s = red[tid] + red[64 + tid] + red[128 + tid] + red[192 + tid] + b2h[0];
      int idx = (b * 96 + y) * 320 + x0 + tid;
      out[idx] = s;
      float sg = 1.f / (1.f + expf(-s));
      sg = fminf(fmaxf(sg, 1e-4f), 1.f - 1e-4f);
      sig[idx] = sg;
    }
  }
}

// ---------------- fallback: fp32 head2 ----------------
__global__ __launch_bounds__(256) void head2_kernel(
    const float* __restrict__ feat, const float* __restrict__ ws,
    const float* __restrict__ b1h, const float* __restrict__ b1o, const float* __restrict__ b1s,
    const float* __restrict__ w2h, const float* __restrict__ w2o, const float* __restrict__ w2s,
    const float* __restrict__ b2h, const float* __restrict__ b2o, const float* __restrict__ b2s,
    float* __restrict__ out)
{
  __shared__ float xs[32 * 10 * 34];
  const int tid = threadIdx.x;
  const int tx = tid & 31, ty = tid >> 5;
  const int x0 = blockIdx.x * 32, y0 = blockIdx.y * 8, bz = blockIdx.z;
  const int px = x0 + tx, py = y0 + ty;
  const float* w1r = ws + WS_W1R;

  #pragma unroll 1
  for (int br = 0; br < 3; ++br) {
    const float* wr = w1r + br * 147456;
    const float* b1 = br == 0 ? b1h : (br == 1 ? b1o : b1s);
    const float* w2 = br == 0 ? w2h : (br == 1 ? w2o : w2s);
    const int cout = (br == 0) ? 1 : 2;
    float acc0 = 0.f, acc1 = 0.f;
    #pragma unroll 1
    for (int c0 = 0; c0 < 256; c0 += 64) {
      float part[64];
      #pragma unroll
      for (int j = 0; j < 64; ++j) part[j] = 0.f;
      #pragma unroll 1
      for (int cc = 0; cc < 2; ++cc) {
        for (int i = tid; i < 32 * 10 * 34; i += 256) {
          int ci = i / 340; int rr = i - ci * 340; int ry = rr / 34; int rx = rr - ry * 34;
          int gy = y0 + ry - 1, gx = x0 + rx - 1;
          float v = 0.f;
          if ((unsigned)gy < 96u && (unsigned)gx < 320u)
            v = feat[((bz * 64 + cc * 32 + ci) * 96 + gy) * 320 + gx];
          xs[i] = v;
        }
        __syncthreads();
        #pragma unroll 1
        for (int ci = 0; ci < 32; ++ci) {
          const float* wp = wr + ((cc * 32 + ci) * 9) * 256 + c0;
          const float* xb = &xs[ci * 340 + ty * 34 + tx];
          #pragma unroll
          for (int k = 0; k < 9; ++k) {
            float xv = xb[(k / 3) * 34 + (k % 3)];
            const float* wk = wp + k * 256;
            #pragma unroll
            for (int j = 0; j < 64; ++j) part[j] = fmaf(wk[j], xv, part[j]);
          }
        }
        __syncthreads();
      }
      #pragma unroll
      for (int j = 0; j < 64; ++j) {
        float yv = part[j] + b1[c0 + j];
        yv = yv > 0.f ? yv : 0.f;
        acc0 = fmaf(w2[c0 + j], yv, acc0);
        if (cout > 1) acc1 = fmaf(w2[256 + c0 + j], yv, acc1);
      }
    }
    if (br == 0) {
      out[(bz * 96 + py) * 320 + px] = acc0 + b2h[0];
    } else if (br == 1) {
      out[OFF_O2 + ((bz * 2 + 0) * 96 + py) * 320 + px] = acc0 + b2o[0];
      out[OFF_O2 + ((bz * 2 + 1) * 96 + py) * 320 + px] = acc1 + b2o[1];
    } else {
      out[OFF_S2 + ((bz * 2 + 0) * 96 + py) * 320 + px] = acc0 + b2s[0];
      out[OFF_S2 + ((bz * 2 + 1) * 96 + py) * 320 + px] = acc1 + b2s[1];
    }
  }
}

// ---------------- NMS ----------------
__global__ void nms_sig_kernel(const float* __restrict__ out, float* __restrict__ sig)
{
  int i = blockIdx.x * 256 + threadIdx.x;
  if (i >= 8 * 30720) return;
  float s = 1.f / (1.f + expf(-out[i]));
  s = s < 1e-4f ? 1e-4f : s;
  float hi = 1.f - 1e-4f;
  sig[i] = s > hi ? hi : s;
}

__global__ void nms_max_kernel(const float* __restrict__ sig, float* __restrict__ keep)
{
  int i = blockIdx.x * 256 + threadIdx.x;
  if (i >= 8 * 30720) return;
  int b = i / 30720; int r = i - b * 30720; int y = r / 320; int x = r - y * 320;
  const float* sb = sig + b * 30720;
  float v = sb[y * 320 + x];
  float m = v;
  for (int dy = -1; dy <= 1; ++dy)
    for (int dx = -1; dx <= 1; ++dx) {
      int yy = y + dy, xx = x + dx;
      if (yy >= 0 && yy < 96 && xx >= 0 && xx < 320) m = fmaxf(m, sb[yy * 320 + xx]);
    }
  keep[i] = (m == v) ? v : 0.f;
}

// ---------------- per-batch top-50 (wave-shuffle argmax) + fused boxes ----------------
__global__ __launch_bounds__(256) void topk_kernel(float* ws, const float* __restrict__ out,
                                                   const float* __restrict__ coord_ranges,
                                                   const float* __restrict__ calibs)
{
  constexpr int CAP = 6144;
  __shared__ float cv[CAP];
  __shared__ int   cix[CAP];
  __shared__ int   cnt;
  __shared__ float wv_[4];
  __shared__ int   wi_[4];
  __shared__ int   wsl[4];
  int b = blockIdx.x, tid = threadIdx.x;
  int lane = tid & 63, wid = tid >> 6;
  if (tid == 0) cnt = 0;
  __syncthreads();
  const float* kb = ws + WS_KEEP + b * 30720;
  for (int i = tid; i < 30720; i += 256) {
    float v = kb[i];
    if (v > 0.f) {
      int pos = atomicAdd(&cnt, 1);
      if (pos < CAP) { cv[pos] = v; cix[pos] = i; }
    }
  }
  __syncthreads();
  int ncand = cnt < CAP ? cnt : CAP;
  int* inds = (int*)(ws + WS_INDS);
  for (int k = 0; k < 50; ++k) {
    float bv = -1.f; int bi = 0x7fffffff; int bs = -1;
    for (int i = tid; i < ncand; i += 256) {
      float v = cv[i]; int id = cix[i];
      if (v > bv || (v == bv && id < bi)) { bv = v; bi = id; bs = i; }
    }
    #pragma unroll
    for (int m = 1; m < 64; m <<= 1) {
      float ov = __shfl_xor(bv, m);
      int oi = __shfl_xor(bi, m);
      int os_ = __shfl_xor(bs, m);
      if (ov > bv || (ov == bv && oi < bi)) { bv = ov; bi = oi; bs = os_; }
    }
    if (lane == 0) { wv_[wid] = bv; wi_[wid] = bi; wsl[wid] = bs; }
    __syncthreads();
    if (tid == 0) {
      float fv = wv_[0]; int fi = wi_[0]; int fs = wsl[0];
      #pragma unroll
      for (int t = 1; t < 4; ++t) {
        if (wv_[t] > fv || (wv_[t] == fv && wi_[t] < fi)) { fv = wv_[t]; fi = wi_[t]; fs = wsl[t]; }
      }
      inds[b * 50 + k] = fi;
      if (fs >= 0) cv[fs] = -1.f;
    }
    __syncthreads();
  }
  // ---- fused boxes for this batch ----
  if (tid < 50) {
    int n = b * 50 + tid;
    int idx = inds[n];
    int iy = idx / 320, ix = idx - iy * 320;
    float o2x = out[OFF_O2 + ((b * 2 + 0) * 96 + iy) * 320 + ix];
    float o2y = out[OFF_O2 + ((b * 2 + 1) * 96 + iy) * 320 + ix];
    float sw  = out[OFF_S2 + ((b * 2 + 0) * 96 + iy) * 320 + ix];
    float sh  = out[OFF_S2 + ((b * 2 + 1) * 96 + iy) * 320 + ix];
    float cx = (float)ix + o2x, cy = (float)iy + o2y;
    float x1 = cx - sw * 0.5f, y1 = cy - sh * 0.5f, x2 = cx + sw * 0.5f, y2 = cy + sh * 0.5f;
    ws[WS_BOX + n * 4 + 0] = x1; ws[WS_BOX + n * 4 + 1] = y1;
    ws[WS_BOX + n * 4 + 2] = x2; ws[WS_BOX + n * 4 + 3] = y2;
    float cr00 = coord_ranges[b * 4 + 0], cr01 = coord_ranges[b * 4 + 1];
    float sx = coord_ranges[b * 4 + 2] - cr00, sy = coord_ranges[b * 4 + 3] - cr01;
    float x1r = x1 / 320.f * sx + cr00, y1r = y1 / 96.f * sy + cr01;
    float x2r = x2 / 320.f * sx + cr00, y2r = y2 / 96.f * sy + cr01;
    const float* cl = calibs + b * 12;
    float fu = cl[0], cu = cl[2], bxp = cl[3] / (-fu);
    float fv2 = cl[5], cvv = cl[6], byp = cl[7] / (-fv2);
    float p1x = (x1r - cu) / fu + bxp, p1y = (y1r - cvv) / fv2 + byp;
    float p2x = (x2r - cu) / fu + bxp, p2y = (y2r - cvv) / fv2 + byp;
    #pragma unroll
    for (int j = 0; j < 7; ++j) {
      float t = (float)j / 6.f;
      ws[WS_XS7 + n * 7 + j] = p1x + t * (p2x - p1x);
      ws[WS_YS7 + n * 7 + j] = p1y + t * (p2y - p1y);
    }
    ws[WS_FU + n] = fu;
    ws[WS_H2D + n] = fmaxf(y2r - y1r, 1.f);
  }
}

// ---------------- ROI-align + build roi_full (fp32) + fused fp16 A3 pack ----------------
__global__ __launch_bounds__(256) void roi_kernel(const float* __restrict__ feat, int fast3, float* ws)
{
  int n = blockIdx.x;
  int tid = threadIdx.x;
  __shared__ int   iy0[14], iy1[14], ix0[14], ix1[14];
  __shared__ float fy[14], fx[14], vy[14], vx[14];
  float bx1 = ws[WS_BOX + n * 4], by1 = ws[WS_BOX + n * 4 + 1];
  float bx2 = ws[WS_BOX + n * 4 + 2], by2 = ws[WS_BOX + n * 4 + 3];
  if (tid < 14) {
    float bh = fmaxf(by2 - by1, 1.f) / 7.f;
    float g = ((float)tid + 0.5f) * 0.5f;
    float c = by1 + g * bh;
    vy[tid] = (c >= -1.f && c <= 96.f) ? 1.f : 0.f;
    c = fminf(fmaxf(c, 0.f), 95.f);
    int i0 = (int)floorf(c);
    iy0[tid] = i0; iy1[tid] = (i0 + 1 < 95) ? i0 + 1 : 95;
    fy[tid] = c - (float)i0;
  } else if (tid < 28) {
    int t = tid - 14;
    float bw = fmaxf(bx2 - bx1, 1.f) / 7.f;
    float g = ((float)t + 0.5f) * 0.5f;
    float c = bx1 + g * bw;
    vx[t] = (c >= -1.f && c <= 320.f) ? 1.f : 0.f;
    c = fminf(fmaxf(c, 0.f), 319.f);
    int i0 = (int)floorf(c);
    ix0[t] = i0; ix1[t] = (i0 + 1 < 319) ? i0 + 1 : 319;
    fx[t] = c - (float)i0;
  }
  __syncthreads();
  int bsel = n / 50;
  const float* fbase = feat + bsel * 64 * 30720;
  float* rf = ws + WS_ROIF + n * 3381;
  for (int i = tid; i < 64 * 49; i += 256) {
    int c = i / 49, p = i - c * 49;
    int oy = p / 7, ox = p - oy * 7;
    const float* fb = fbase + c * 30720;
    float s = 0.f;
    #pragma unroll
    for (int sy2 = 0; sy2 < 2; ++sy2) {
      #pragma unroll
      for (int sx2 = 0; sx2 < 2; ++sx2) {
        int jy = oy * 2 + sy2, jx = ox * 2 + sx2;
        const float* r0 = fb + iy0[jy] * 320;
        const float* r1 = fb + iy1[jy] * 320;
        float gy = fy[jy], gx = fx[jx];
        float v00 = r0[ix0[jx]], v01 = r0[ix1[jx]], v10 = r1[ix0[jx]], v11 = r1[ix1[jx]];
        float v = v00 * (1.f - gy) * (1.f - gx) + v01 * (1.f - gy) * gx
                + v10 * gy * (1.f - gx) + v11 * gy * gx;
        s += v * vy[jy] * vx[jx];
      }
    }
    rf[c * 49 + p] = s * 0.25f;
  }
  if (tid < 5 * 49) {
    int ch = tid / 49, p = tid - ch * 49;
    int oy = p / 7, ox = p - oy * 7;
    float v;
    if (ch == 0) v = ws[WS_XS7 + n * 7 + ox];
    else if (ch == 1) v = ws[WS_YS7 + n * 7 + oy];
    else if (ch == 2) v = 1.f;
    else v = 0.f;
    rf[(64 + ch) * 49 + p] = v;
  }
  if (fast3) {
    __syncthreads();
    unsigned short* a3 = (unsigned short*)(ws + WS_A3) + (size_t)n * 7776;
    for (int t = 0; t < 31; ++t) {
      int i = t * 256 + tid;
      if (i < 7776) {
        int pr = i / 96, ch = i - pr * 96;
        int py = pr / 9, px = pr - py * 9;
        float v = 0.f;
        if (py >= 1 && py <= 7 && px >= 1 && px <= 7 && ch < 69)
          v = rf[ch * 49 + (py - 1) * 7 + (px - 1)];
        a3[i] = __builtin_bit_cast(unsigned short, (_Float16)v);
      }
    }
  }
}

// ---------------- fast3: head3 MFMA (1 roi x 1 branch per block) ----------------
__global__ __launch_bounds__(256, 2) void head3m_kernel(
    float* __restrict__ ws,
    const float* __restrict__ b1d, const float* __restrict__ b1o3, const float* __restrict__ b1s3, const float* __restrict__ b1hd,
    const float* __restrict__ w2d, const float* __restrict__ w2o3, const float* __restrict__ w2s3, const float* __restrict__ w2hd,
    const float* __restrict__ b2d, const float* __restrict__ b2o3, const float* __restrict__ b2s3, const float* __restrict__ b2hd,
    float* __restrict__ out)
{
  __shared__ unsigned char A[81 * 104 * 2];
  __shared__ float ym[256];
  const int tid = threadIdx.x;
  const int l = tid & 63, w = tid >> 6;
  const int l15 = l & 15, lg = l >> 4;
  const int n = blockIdx.x;
  const int br = blockIdx.y;
  const unsigned short* a3 = (const unsigned short*)(ws + WS_A3) + (size_t)n * 7776;
  const _Float16* wp3 = (const _Float16*)(ws + WS_WPACK3);

  #pragma unroll
  for (int t = 0; t < 4; ++t) {
    int u = t * 256 + tid;
    if (u < 972) {
      int row = u / 12, cu = u - row * 12;
      u32x4 v = *(const u32x4*)(a3 + u * 8);
      *(u32x4*)(A + (row * 104 + cu * 8) * 2) = v;
    }
  }
  __syncthreads();

  int aB[4];
  #pragma unroll
  for (int pf = 0; pf < 4; ++pf) {
    int p = pf * 16 + l15;
    int rb = (p < 49) ? ((p / 7) * 9 + (p % 7)) : 0;
    aB[pf] = rb * 208 + lg * 16;
  }

  const float* b1 = br == 0 ? b1d : (br == 1 ? b1o3 : (br == 2 ? b1s3 : b1hd));
  const float* w2 = br == 0 ? w2d : (br == 1 ? w2o3 : (br == 2 ? w2s3 : w2hd));
  const float* b2 = br == 0 ? b2d : (br == 1 ? b2o3 : (br == 2 ? b2s3 : b2hd));
  const int cout = br == 0 ? 2 : (br == 1 ? 2 : (br == 2 ? 4 : 24));

  f32x4 acc[4][4];
  #pragma unroll
  for (int i = 0; i < 4; ++i)
    #pragma unroll
    for (int j = 0; j < 4; ++j) acc[i][j] = (f32x4)(0.f);

  const _Float16* wB3 = wp3 + (((long long)(br * 27) * 16 + w * 4) * 4 + lg) * 128 + l15 * 8;

  #pragma unroll
  for (int s = 0; s < 27; ++s) {
    const int tap = s / 3, cc = s - tap * 3;
    const int ky = tap / 3, kx = tap - ky * 3;
    const int stepOff = (ky * 9 + kx) * 208 + cc * 64;
    f16x8 af[4], bf[4];
    #pragma unroll
    for (int pf = 0; pf < 4; ++pf)
      af[pf] = *(const f16x8*)(A + aB[pf] + stepOff);
    #pragma unroll
    for (int nf = 0; nf < 4; ++nf)
      bf[nf] = *(const f16x8*)(wB3 + s * 8192 + nf * 512);
    #pragma unroll
    for (int pf = 0; pf < 4; ++pf)
      #pragma unroll
      for (int nf = 0; nf < 4; ++nf)
        acc[pf][nf] = __builtin_amdgcn_mfma_f32_16x16x32_f16(af[pf], bf[nf], acc[pf][nf], 0, 0, 0);
  }

  #pragma unroll
  for (int nf = 0; nf < 4; ++nf) {
    int nn = w * 64 + nf * 16 + l15;
    float b1n = b1[nn];
    float scn = ws[WS_BNSC + br * 256 + nn];
    float shn = ws[WS_BNSH + br * 256 + nn];
    float local = 0.f;
    #pragma unroll
    for (int pf = 0; pf < 4; ++pf) {
      #pragma unroll
      for (int rr = 0; rr < 4; ++rr) {
        int p = pf * 16 + lg * 4 + rr;
        float yv = (acc[pf][nf][rr] + b1n) * scn + shn;
        yv = yv > 0.f ? yv : 0.f;
        local += (p < 49) ? yv : 0.f;
      }
    }
    local += __shfl_xor(local, 16);
    local += __shfl_xor(local, 32);
    if (lg == 0) ym[nn] = local;
  }
  __syncthreads();
  for (int o = w; o < cout; o += 4) {
    float p = 0.f;
    #pragma unroll
    for (int t = 0; t < 4; ++t) p = fmaf(w2[o * 256 + t * 64 + l], ym[t * 64 + l], p);
    p *= (1.f / 49.f);
    #pragma unroll
    for (int off = 32; off > 0; off >>= 1) p += __shfl_down(p, off);
    if (l == 0) {
      float v = p + b2[o];
      if (br == 0) ws[WS_DNO + n * 2 + o] = v;
      else if (br == 1) out[OFF_O3D + n * 2 + o] = v;
      else if (br == 2) { if (o < 3) out[OFF_S3D + n * 3 + o] = v; else out[OFF_H3D + n] = v; }
      else out[OFF_HEAD + n * 24 + o] = v;
    }
  }
}

// ---------------- fallback: fp32 head3 ----------------
__global__ __launch_bounds__(256) void head3_kernel(
    float* ws,
    const float* __restrict__ b1d, const float* __restrict__ b1o3, const float* __restrict__ b1s3, const float* __restrict__ b1hd,
    const float* __restrict__ w2d, const float* __restrict__ w2o3, const float* __restrict__ w2s3, const float* __restrict__ w2hd,
    const float* __restrict__ b2d, const float* __restrict__ b2o3, const float* __restrict__ b2s3, const float* __restrict__ b2hd,
    float* __restrict__ out)
{
  int n = blockIdx.x, br = blockIdx.y;
  int c = threadIdx.x;
  __shared__ float ym[256];
  const float* wt = ws + WS_W1T + br * 158976;
  const float* b1 = br == 0 ? b1d : (br == 1 ? b1o3 : (br == 2 ? b1s3 : b1hd));
  const float* w2 = br == 0 ? w2d : (br == 1 ? w2o3 : (br == 2 ? w2s3 : w2hd));
  const float* b2 = br == 0 ? b2d : (br == 1 ? b2o3 : (br == 2 ? b2s3 : b2hd));
  const int cout = br == 0 ? 2 : (br == 1 ? 2 : (br == 2 ? 4 : 24));
  const float* xin0 = ws + WS_ROIF + n * 3381;

  float acc[49];
  #pragma unroll
  for (int i = 0; i < 49; ++i) acc[i] = 0.f;

  #pragma unroll 1
  for (int ci = 0; ci < 69; ++ci) {
    float wv[9];
    #pragma unroll
    for (int k = 0; k < 9; ++k) wv[k] = wt[(ci * 9 + k) * 256 + c];
    const float* xin = xin0 + ci * 49;
    #pragma unroll
    for (int y = 0; y < 7; ++y) {
      float xr[9];
      xr[0] = 0.f; xr[8] = 0.f;
      #pragma unroll
      for (int q = 0; q < 7; ++q) xr[q + 1] = xin[y * 7 + q];
      #pragma unroll
      for (int ky = 0; ky < 3; ++ky) {
        int pyy = y + 1 - ky;
        if (pyy >= 0 && pyy < 7) {
          #pragma unroll
          for (int kx = 0; kx < 3; ++kx) {
            float w = wv[ky * 3 + kx];
            #pragma unroll
            for (int pxx = 0; pxx < 7; ++pxx)
              acc[pyy * 7 + pxx] = fmaf(w, xr[pxx + kx], acc[pyy * 7 + pxx]);
          }
        }
      }
    }
  }
  float b1c = b1[c];
  float sc = ws[WS_BNSC + br * 256 + c];
  float sh = ws[WS_BNSH + br * 256 + c];
  float sum = 0.f;
  #pragma unroll
  for (int i = 0; i < 49; ++i) {
    float yv = (acc[i] + b1c) * sc + sh;
    sum += yv > 0.f ? yv : 0.f;
  }
  ym[c] = sum / 49.f;
  __syncthreads();
  int lane = c & 63, wid = c >> 6;
  for (int o = wid; o < cout; o += 4) {
    float p = 0.f;
    #pragma unroll
    for (int t = 0; t < 4; ++t) p = fmaf(w2[o * 256 + t * 64 + lane], ym[t * 64 + lane], p);
    #pragma unroll
    for (int off = 32; off > 0; off >>= 1) p += __shfl_down(p, off);
    if (lane == 0) {
      float v = p + b2[o];
      if (br == 0) ws[WS_DNO + n * 2 + o] = v;
      else if (br == 1) out[OFF_O3D + n * 2 + o] = v;
      else if (br == 2) { if (o < 3) out[OFF_S3D + n * 3 + o] = v; else out[OFF_H3D + n] = v; }
      else out[OFF_HEAD + n * 24 + o] = v;
    }
  }
}

// ---------------- depth epilogue ----------------
__global__ void depth_kernel(const float* ws, const float* __restrict__ mean_size, float* __restrict__ out)
{
  int n = blockIdx.x * 256 + threadIdx.x;
  if (n >= 400) return;
  float h3d = out[OFF_H3D + n];
  float s30 = out[OFF_S3D + n * 3];
  float size0 = mean_size[0] + s30;
  float f = ws[WS_FU + n], h = ws[WS_H2D + n];
  float dgeo = size0 / h * f;
  float geo = h3d + 2.f * (logf(f) - logf(h));
  float a = ws[WS_DNO + n * 2 + 1];
  float mx = fmaxf(a, geo);
  float nls = mx + logf(expf(a - mx) + expf(geo - mx));
  float sg = 1.f / (1.f + expf(-ws[WS_DNO + n * 2]));
  out[OFF_DEPTH + n * 2] = 1.f / (sg + 1e-6f) - 1.f + dgeo;
  out[OFF_DEPTH + n * 2 + 1] = nls;
}

// ---------------- launch ----------------
extern "C" void kernel_launch(void* const* d_in, const int* in_sizes, int n_in,
                              void* d_out, int out_size, void* d_ws, size_t ws_size,
                              hipStream_t stream)
{
  const float* feat         = (const float*)d_in[0];
  const float* coord_ranges = (const float*)d_in[1];
  const float* calibs       = (const float*)d_in[2];
  const float* mean_size    = (const float*)d_in[3];
  const float* hm_w1 = (const float*)d_in[4];
  const float* hm_b1 = (const float*)d_in[5];
  const float* hm_w2 = (const float*)d_in[6];
  const float* hm_b2 = (const float*)d_in[7];
  const float* o2_w1 = (const float*)d_in[8];
  const float* o2_b1 = (const float*)d_in[9];
  const float* o2_w2 = (const float*)d_in[10];
  const float* o2_b2 = (const float*)d_in[11];
  const float* s2_w1 = (const float*)d_in[12];
  const float* s2_b1 = (const float*)d_in[13];
  const float* s2_w2 = (const float*)d_in[14];
  const float* s2_b2 = (const float*)d_in[15];
  const float* dep_w1 = (const float*)d_in[16];
  const float* dep_b1 = (const float*)d_in[17];
  const float* dep_g  = (const float*)d_in[18];
  const float* dep_be = (const float*)d_in[19];
  const float* dep_m  = (const float*)d_in[20];
  const float* dep_v  = (const float*)d_in[21];
  const float* dep_w2 = (const float*)d_in[22];
  const float* dep_b2 = (const float*)d_in[23];
  const float* o3_w1 = (const float*)d_in[24];
  const float* o3_b1 = (const float*)d_in[25];
  const float* o3_g  = (const float*)d_in[26];
  const float* o3_be = (const float*)d_in[27];
  const float* o3_m  = (const float*)d_in[28];
  const float* o3_v  = (const float*)d_in[29];
  const float* o3_w2 = (const float*)d_in[30];
  const float* o3_b2 = (const float*)d_in[31];
  const float* s3_w1 = (const float*)d_in[32];
  const float* s3_b1 = (const float*)d_in[33];
  const float* s3_g  = (const float*)d_in[34];
  const float* s3_be = (const float*)d_in[35];
  const float* s3_m  = (const float*)d_in[36];
  const float* s3_v  = (const float*)d_in[37];
  const float* s3_w2 = (const float*)d_in[38];
  const float* s3_b2 = (const float*)d_in[39];
  const float* hd_w1 = (const float*)d_in[40];
  const float* hd_b1 = (const float*)d_in[41];
  const float* hd_g  = (const float*)d_in[42];
  const float* hd_be = (const float*)d_in[43];
  const float* hd_m  = (const float*)d_in[44];
  const float* hd_v  = (const float*)d_in[45];
  const float* hd_w2 = (const float*)d_in[46];
  const float* hd_b2 = (const float*)d_in[47];

  float* out = (float*)d_out;
  float* ws  = (float*)d_ws;
  bool fast  = (long long)ws_size >= FAST_REQ_BYTES;
  bool fast3 = (long long)ws_size >= FAST3_REQ_BYTES;

  if (fast) {
    int nprep = 7820 + (fast3 ? 3456 : 0);
    prep_kernel<<<dim3(nprep), 256, 0, stream>>>(feat,
        hm_w1, o2_w1, s2_w1, dep_w1, o3_w1, s3_w1, hd_w1,
        dep_g, dep_be, dep_m, dep_v, o3_g, o3_be, o3_m, o3_v,
        s3_g, s3_be, s3_m, s3_v, hd_g, hd_be, hd_m, hd_v, ws);
    if (!fast3) {
      repack_kernel<<<dim3((3 * 147456 + 4 * 158976 + 1024 + 255) / 256), 256, 0, stream>>>(
          hm_w1, o2_w1, s2_w1, dep_w1, o3_w1, s3_w1, hd_w1,
          dep_g, dep_be, dep_m, dep_v, o3_g, o3_be, o3_m, o3_v,
          s3_g, s3_be, s3_m, s3_v, hd_g, hd_be, hd_m, hd_v,
          1, 0, ws);
    }
    head2f_kernel<<<dim3(3840), 256, 0, stream>>>(ws,
        o2_b1, s2_b1, hm_b1, o2_w2, s2_w2, hm_w2, o2_b2, s2_b2, hm_b2, out, ws + WS_SIG);
  } else {
    repack_kernel<<<dim3((3 * 147456 + 4 * 158976 + 1024 + 255) / 256), 256, 0, stream>>>(
        hm_w1, o2_w1, s2_w1, dep_w1, o3_w1, s3_w1, hd_w1,
        dep_g, dep_be, dep_m, dep_v, o3_g, o3_be, o3_m, o3_v,
        s3_g, s3_be, s3_m, s3_v, hd_g, hd_be, hd_m, hd_v,
        0, 0, ws);
    head2_kernel<<<dim3(10, 12, 8), 256, 0, stream>>>(feat, ws,
        hm_b1, o2_b1, s2_b1, hm_w2, o2_w2, s2_w2, hm_b2, o2_b2, s2_b2, out);
    nms_sig_kernel<<<dim3(960), 256, 0, stream>>>(out, ws + WS_SIG);
  }

  nms_max_kernel<<<dim3(960), 256, 0, stream>>>(ws + WS_SIG, ws + WS_KEEP);
  topk_kernel<<<dim3(8), 256, 0, stream>>>(ws, out, coord_ranges, calibs);
  roi_kernel<<<dim3(400), 256, 0, stream>>>(feat, fast3 ? 1 : 0, ws);
  if (fast3) {
    head3m_kernel<<<dim3(400, 4), 256, 0, stream>>>(ws,
        dep_b1, o3_b1, s3_b1, hd_b1, dep_w2, o3_w2, s3_w2, hd_w2,
        dep_b2, o3_b2, s3_b2, hd_b2, out);
  } else {
    head3_kernel<<<dim3(400, 4), 256, 0, stream>>>(ws,
        dep_b1, o3_b1, s3_b1, hd_b1, dep_w2, o3_w2, s3_w2, hd_w2,
        dep_b2, o3_b2, s3_b2, hd_b2, out);
  }
  depth_kernel<<<dim3(2), 256, 0, stream>>>(ws, mean_size, out);
}

// Round 15
// 545.227 us; speedup vs baseline: 1.1275x; 1.0107x over previous
//
#include <hip/hip_runtime.h>

// ---------------- problem constants ----------------
// B=8 C=64 H=96 W=320 K=50 HEAD=256 CIN3=69

// d_out offsets (floats)
constexpr int OFF_O2    = 245760;
constexpr int OFF_S2    = 737280;
constexpr int OFF_HEAD  = 1228800;
constexpr int OFF_DEPTH = 1238400;
constexpr int OFF_O3D   = 1239200;
constexpr int OFF_S3D   = 1240000;
constexpr int OFF_H3D   = 1241200;

// workspace offsets (floats)
constexpr int WS_W1T  = 0;
constexpr int WS_BNSC = 635904;
constexpr int WS_BNSH = 636928;
constexpr int WS_KEEP = 637952;
constexpr int WS_INDS = 883712;
constexpr int WS_BOX  = 884112;
constexpr int WS_XS7  = 885712;
constexpr int WS_YS7  = 888512;
constexpr int WS_FU   = 891312;
constexpr int WS_H2D  = 891712;
constexpr int WS_DNO  = 892112;
constexpr int WS_ROIF = 892912;
constexpr int WS_SIG  = WS_ROIF;
constexpr int WS_W1R  = 2245312;
constexpr int WS_WPACK2 = 2245312;
constexpr int WS_FEATH  = 2540224;
constexpr int WS_FEATL  = 10618560;
constexpr long long FAST_REQ_BYTES = 18696896LL * 4;
constexpr int WS_WPACK3 = 18696896;
constexpr int WS_A3     = 19139264;
constexpr long long FAST3_REQ_BYTES = 20694464LL * 4;

typedef __attribute__((ext_vector_type(4))) float f32x4;
typedef __attribute__((ext_vector_type(8))) _Float16 f16x8;
typedef __attribute__((ext_vector_type(4))) unsigned int u32x4;

// ---------------- fallback: weight repack + BN prep ----------------
__global__ void repack_kernel(
    const float* __restrict__ w2h, const float* __restrict__ w2o, const float* __restrict__ w2s,
    const float* __restrict__ w3d, const float* __restrict__ w3o, const float* __restrict__ w3s, const float* __restrict__ w3h,
    const float* __restrict__ g0, const float* __restrict__ be0, const float* __restrict__ m0, const float* __restrict__ v0,
    const float* __restrict__ g1, const float* __restrict__ be1, const float* __restrict__ m1, const float* __restrict__ v1,
    const float* __restrict__ g2, const float* __restrict__ be2, const float* __restrict__ m2, const float* __restrict__ v2,
    const float* __restrict__ g3, const float* __restrict__ be3, const float* __restrict__ m3, const float* __restrict__ v3,
    int skip2, int skip3, float* __restrict__ ws)
{
  int i = blockIdx.x * 256 + threadIdx.x;
  if (i < 3 * 147456) {
    if (skip2) return;
    int br = i / 147456, r = i - br * 147456, q = r >> 8, c = r & 255;
    const float* src = br == 0 ? w2h : (br == 1 ? w2o : w2s);
    ws[WS_W1R + i] = src[c * 576 + q];
  } else if (i < 3 * 147456 + 4 * 158976) {
    if (skip3) return;
    int j = i - 3 * 147456;
    int br = j / 158976, r = j - br * 158976, q = r >> 8, c = r & 255;
    const float* src = br == 0 ? w3d : (br == 1 ? w3o : (br == 2 ? w3s : w3h));
    ws[WS_W1T + j] = src[c * 621 + q];
  } else {
    int j = i - (3 * 147456 + 4 * 158976);
    if (j < 1024) {
      int br = j >> 8, c = j & 255;
      const float* g  = br == 0 ? g0  : (br == 1 ? g1  : (br == 2 ? g2  : g3));
      const float* be = br == 0 ? be0 : (br == 1 ? be1 : (br == 2 ? be2 : be3));
      const float* m  = br == 0 ? m0  : (br == 1 ? m1  : (br == 2 ? m2  : m3));
      const float* v  = br == 0 ? v0  : (br == 1 ? v1  : (br == 2 ? v2  : v3));
      float sc = g[c] * rsqrtf(v[c] + 1e-5f);
      ws[WS_BNSC + j] = sc;
      ws[WS_BNSH + j] = be[c] - m[c] * sc;
    }
  }
}

// ---------------- fast path: fused prep (transpose + wpack2 + pad_zero + BN + wpack3) ----------------
__global__ __launch_bounds__(256) void prep_kernel(
    const float* __restrict__ feat,
    const float* __restrict__ hm_w1, const float* __restrict__ o2_w1, const float* __restrict__ s2_w1,
    const float* __restrict__ w3d, const float* __restrict__ w3o, const float* __restrict__ w3s, const float* __restrict__ w3h,
    const float* __restrict__ g0, const float* __restrict__ be0, const float* __restrict__ m0, const float* __restrict__ v0,
    const float* __restrict__ g1, const float* __restrict__ be1, const float* __restrict__ m1, const float* __restrict__ v1,
    const float* __restrict__ g2, const float* __restrict__ be2, const float* __restrict__ m2, const float* __restrict__ v2,
    const float* __restrict__ g3, const float* __restrict__ be3, const float* __restrict__ m3, const float* __restrict__ v3,
    float* __restrict__ ws)
{
  __shared__ unsigned short T2[2][64 * 65];
  const int bid = blockIdx.x;
  const int tid = threadIdx.x;

  if (bid < 3840) {
    int b = bid / 480; int r = bid % 480; int y = r / 5; int x0 = (r % 5) * 64;
    int lx = tid & 63, grp = tid >> 6;
    #pragma unroll
    for (int it = 0; it < 16; ++it) {
      int ci = it * 4 + grp;
      float v = feat[(((b * 64 + ci) * 96 + y) * 320) + x0 + lx];
      _Float16 h = (_Float16)v;
      _Float16 l = (_Float16)(v - (float)h);
      T2[0][lx * 65 + ci] = __builtin_bit_cast(unsigned short, h);
      T2[1][lx * 65 + ci] = __builtin_bit_cast(unsigned short, l);
    }
    __syncthreads();
    unsigned int* fH = (unsigned int*)(ws + WS_FEATH);
    unsigned int* fL = (unsigned int*)(ws + WS_FEATL);
    #pragma unroll
    for (int it = 0; it < 16; ++it) {
      int unit = it * 256 + tid;
      int arr = unit >> 11; int un = unit & 2047;
      int x = un >> 5, pr = un & 31;
      unsigned int lo = T2[arr][x * 65 + pr * 2];
      unsigned int hi = T2[arr][x * 65 + pr * 2 + 1];
      unsigned int val = lo | (hi << 16);
      unsigned int* dst = arr ? fL : fH;
      dst[((b * 98 + y + 1) * 322 + (x0 + x + 1)) * 32 + pr] = val;
    }
  } else if (bid < 6144) {
    int i = (bid - 3840) * 256 + tid;
    int br = i / 147456; int r = i - br * 147456;
    int c = r / 8192; int r2 = r - c * 8192;
    int n = r2 >> 5; int kk = r2 & 31;
    int kg = c * 32 + kk;
    int tap = kg >> 6, ci = kg & 63;
    const float* w1 = (br == 0) ? o2_w1 : (br == 1 ? s2_w1 : hm_w1);
    float v = w1[n * 576 + ci * 9 + tap];
    _Float16 hi = (_Float16)v;
    _Float16 valh;
    if (br == 3) valh = (_Float16)(v - (float)hi);
    else valh = hi;
    unsigned short bits = __builtin_bit_cast(unsigned short, valh);
    long long didx = (((((long long)br * 18 + c) * 16 + (n >> 4)) * 4 + (kk >> 3)) * 128) + (n & 15) * 8 + (kk & 7);
    ((unsigned short*)(ws + WS_WPACK2))[didx] = bits;
  } else if (bid < 7816) {
    int i = (bid - 6144) * 256 + tid;
    if (i < 428032) {
      int arr = i / 214016; int r = i - arr * 214016;
      int px = r >> 5, q = r & 31;
      int b = px / 836, pr = px - b * 836;
      int yy, xx;
      if (pr < 322) { yy = 0; xx = pr; }
      else if (pr < 644) { yy = 97; xx = pr - 322; }
      else { int t = pr - 644; yy = 1 + (t >> 1); xx = (t & 1) * 321; }
      unsigned int* dst = (unsigned int*)(ws + (arr ? WS_FEATL : WS_FEATH));
      dst[((b * 98 + yy) * 322 + xx) * 32 + q] = 0u;
    }
  } else if (bid < 7820) {
    int j = (bid - 7816) * 256 + tid;
    if (j < 1024) {
      int br = j >> 8, c = j & 255;
      const float* g  = br == 0 ? g0  : (br == 1 ? g1  : (br == 2 ? g2  : g3));
      const float* be = br == 0 ? be0 : (br == 1 ? be1 : (br == 2 ? be2 : be3));
      const float* m  = br == 0 ? m0  : (br == 1 ? m1  : (br == 2 ? m2  : m3));
      const float* v  = br == 0 ? v0  : (br == 1 ? v1  : (br == 2 ? v2  : v3));
      float sc = g[c] * rsqrtf(v[c] + 1e-5f);
      ws[WS_BNSC + j] = sc;
      ws[WS_BNSH + j] = be[c] - m[c] * sc;
    }
  } else {
    int i = (bid - 7820) * 256 + tid;
    if (i < 4 * 27 * 256 * 32) {
      int br = i / 221184; int r = i - br * 221184;
      int s = r / 8192; int r2 = r - s * 8192;
      int n = r2 >> 5; int kk = r2 & 31;
      int tap = s / 3; int cc = s - tap * 3;
      int ch = cc * 32 + kk;
      const float* w1 = br == 0 ? w3d : (br == 1 ? w3o : (br == 2 ? w3s : w3h));
      float v = (ch < 69) ? w1[n * 621 + ch * 9 + tap] : 0.f;
      unsigned short bits = __builtin_bit_cast(unsigned short, (_Float16)v);
      long long didx = (((((long long)br * 27 + s) * 16 + (n >> 4)) * 4 + (kk >> 3)) * 128) + (n & 15) * 8 + (kk & 7);
      ((unsigned short*)(ws + WS_WPACK3))[didx] = bits;
    }
  }
}

// ---- transposed LDS layout: unit (row, x, j) at ((row*8 + j)*66 + x)*16 bytes ----

// ---------------- fast path: fused head2 (o2, s2, hm) + setprio on MFMA clusters ----------------
__global__ __launch_bounds__(256, 3) void head2f_kernel(
    const float* __restrict__ ws,
    const float* __restrict__ b1o, const float* __restrict__ b1s, const float* __restrict__ b1h,
    const float* __restrict__ w2o, const float* __restrict__ w2s, const float* __restrict__ w2h,
    const float* __restrict__ b2o, const float* __restrict__ b2s, const float* __restrict__ b2h,
    float* __restrict__ out, float* __restrict__ sig)
{
  __shared__ unsigned char tiles[2 * 3 * 8 * 66 * 16];  // hi @0, lo @+25344 = 50688 B
  __shared__ float red[512];
  const int tid = threadIdx.x;
  const int l = tid & 63, w = tid >> 6;
  const int bx = blockIdx.x;
  const int b = bx / 480; int r = bx % 480;
  const int y = r / 5; const int x0 = (r % 5) * 64;
  const unsigned short* fH = (const unsigned short*)(ws + WS_FEATH) + (size_t)b * (98 * 322 * 64);
  const unsigned short* fL = (const unsigned short*)(ws + WS_FEATL) + (size_t)b * (98 * 322 * 64);
  const _Float16* wpk = (const _Float16*)(ws + WS_WPACK2);

  for (int t = 0; t < 13; ++t) {
    int u = t * 256 + tid;
    if (u < 3168) {
      int arr = u >= 1584; int uu = u - arr * 1584;
      int row = uu / 528; int rem = uu - row * 528;
      int x = rem >> 3, j0 = rem & 7;
      const unsigned short* src = arr ? fL : fH;
      u32x4 v = *(const u32x4*)(src + ((y + row) * 322 + (x0 + x)) * 64 + j0 * 8);
      *(u32x4*)(tiles + arr * 25344 + ((row * 8 + j0) * 66 + x) * 16) = v;
    }
  }
  __syncthreads();

  const int l15 = l & 15, lg = l >> 4;
  const int aBase = (lg * 66 + l15) * 16;

  // ---- branches 0,1: o2 / s2 (hi only, 1 product) ----
  #pragma unroll 1
  for (int br = 0; br < 2; ++br) {
    f32x4 acc[4][4];
    #pragma unroll
    for (int i = 0; i < 4; ++i)
      #pragma unroll
      for (int j = 0; j < 4; ++j) acc[i][j] = (f32x4)(0.f);

    const _Float16* wB = wpk + (((long long)(br * 18) * 16 + w * 4) * 4 + lg) * 128 + l15 * 8;

    #pragma unroll
    for (int s = 0; s < 18; ++s) {
      const int tap = s >> 1, half = s & 1;
      const int ky = tap / 3, kx = tap - ky * 3;
      const int stepOff = ((ky * 8 + half * 4) * 66 + kx) * 16;
      f16x8 af[4], bf[4];
      #pragma unroll
      for (int pf = 0; pf < 4; ++pf)
        af[pf] = *(const f16x8*)(tiles + aBase + pf * 256 + stepOff);
      #pragma unroll
      for (int nf = 0; nf < 4; ++nf)
        bf[nf] = *(const f16x8*)(wB + s * 8192 + nf * 512);
      __builtin_amdgcn_s_setprio(1);
      #pragma unroll
      for (int pf = 0; pf < 4; ++pf)
        #pragma unroll
        for (int nf = 0; nf < 4; ++nf)
          acc[pf][nf] = __builtin_amdgcn_mfma_f32_16x16x32_f16(af[pf], bf[nf], acc[pf][nf], 0, 0, 0);
      __builtin_amdgcn_s_setprio(0);
    }

    const float* b1 = br == 0 ? b1o : b1s;
    const float* w2 = br == 0 ? w2o : w2s;
    const float* b2 = br == 0 ? b2o : b2s;
    float b1v_[4], w2v[2][4];
    #pragma unroll
    for (int nf = 0; nf < 4; ++nf) {
      int n = w * 64 + nf * 16 + l15;
      b1v_[nf] = b1[n];
      w2v[0][nf] = w2[n];
      w2v[1][nf] = w2[256 + n];
    }
    __syncthreads();
    #pragma unroll
    for (int pf = 0; pf < 4; ++pf) {
      #pragma unroll
      for (int rr = 0; rr < 4; ++rr) {
        float s0 = 0.f, s1 = 0.f;
        #pragma unroll
        for (int nf = 0; nf < 4; ++nf) {
          float yv = acc[pf][nf][rr] + b1v_[nf];
          yv = yv > 0.f ? yv : 0.f;
          s0 = fmaf(w2v[0][nf], yv, s0);
          s1 = fmaf(w2v[1][nf], yv, s1);
        }
        #pragma unroll
        for (int m = 1; m < 16; m <<= 1) {
          s0 += __shfl_xor(s0, m);
          s1 += __shfl_xor(s1, m);
        }
        if (l15 == 0) {
          int p = pf * 16 + lg * 4 + rr;
          red[(w * 2 + 0) * 64 + p] = s0;
          red[(w * 2 + 1) * 64 + p] = s1;
        }
      }
    }
    __syncthreads();
    if (tid < 128) {
      int p = tid & 63, o = tid >> 6;
      float s = red[(0 * 2 + o) * 64 + p] + red[(1 * 2 + o) * 64 + p] +
                red[(2 * 2 + o) * 64 + p] + red[(3 * 2 + o) * 64 + p] + b2[o];
      int base = (br == 0) ? OFF_O2 : OFF_S2;
      out[base + ((b * 2 + o) * 96 + y) * 320 + x0 + p] = s;
    }
    __syncthreads();
  }

  // ---- branch 2: hm (hi+lo, 3 products) ----
  {
    f32x4 acc[4][4];
    #pragma unroll
    for (int i = 0; i < 4; ++i)
      #pragma unroll
      for (int j = 0; j < 4; ++j) acc[i][j] = (f32x4)(0.f);

    const _Float16* wBH = wpk + (((long long)(2 * 18) * 16 + w * 4) * 4 + lg) * 128 + l15 * 8;
    const _Float16* wBL = wpk + (((long long)(3 * 18) * 16 + w * 4) * 4 + lg) * 128 + l15 * 8;

    #pragma unroll
    for (int s = 0; s < 18; ++s) {
      const int tap = s >> 1, half = s & 1;
      const int ky = tap / 3, kx = tap - ky * 3;
      const int stepOff = ((ky * 8 + half * 4) * 66 + kx) * 16;
      f16x8 ah[4], al[4], bh[4], bl[4];
      #pragma unroll
      for (int pf = 0; pf < 4; ++pf) {
        ah[pf] = *(const f16x8*)(tiles + aBase + pf * 256 + stepOff);
        al[pf] = *(const f16x8*)(tiles + 25344 + aBase + pf * 256 + stepOff);
      }
      #pragma unroll
      for (int nf = 0; nf < 4; ++nf) {
        bh[nf] = *(const f16x8*)(wBH + s * 8192 + nf * 512);
        bl[nf] = *(const f16x8*)(wBL + s * 8192 + nf * 512);
      }
      __builtin_amdgcn_s_setprio(1);
      #pragma unroll
      for (int pf = 0; pf < 4; ++pf)
        #pragma unroll
        for (int nf = 0; nf < 4; ++nf)
          acc[pf][nf] = __builtin_amdgcn_mfma_f32_16x16x32_f16(ah[pf], bh[nf], acc[pf][nf], 0, 0, 0);
      #pragma unroll
      for (int pf = 0; pf < 4; ++pf)
        #pragma unroll
        for (int nf = 0; nf < 4; ++nf)
          acc[pf][nf] = __builtin_amdgcn_mfma_f32_16x16x32_f16(ah[pf], bl[nf], acc[pf][nf], 0, 0, 0);
      #pragma unroll
      for (int pf = 0; pf < 4; ++pf)
        #pragma unroll
        for (int nf = 0; nf < 4; ++nf)
          acc[pf][nf] = __builtin_amdgcn_mfma_f32_16x16x32_f16(al[pf], bh[nf], acc[pf][nf], 0, 0, 0);
      __builtin_amdgcn_s_setprio(0);
    }

    float b1v_[4], w2v[4];
    #pragma unroll
    for (int nf = 0; nf < 4; ++nf) {
      int n = w * 64 + nf * 16 + l15;
      b1v_[nf] = b1h[n];
      w2v[nf] = w2h[n];
    }
    __syncthreads();
    #pragma unroll
    for (int pf = 0; pf < 4; ++pf) {
      #pragma unroll
      for (int rr = 0; rr < 4; ++rr) {
        float s0 = 0.f;
        #pragma unroll
        for (int nf = 0; nf < 4; ++nf) {
          float yv = acc[pf][nf][rr] + b1v_[nf];
          yv = yv > 0.f ? yv : 0.f;
          s0 = fmaf(w2v[nf], yv, s0);
        }
        #pragma unroll
        for (int m = 1; m < 16; m <<= 1) s0 += __shfl_xor(s0, m);
        if (l15 == 0) red[w * 64 + pf * 16 + lg * 4 + rr] = s0;
      }
    }
    __syncthreads();
    if (tid < 64) {
      float s = red[tid] + red[64 + tid] + red[128 + tid] + red[192 + tid] + b2h[0];
      int idx = (b * 96 + y) * 320 + x0 + tid;
      out[idx] = s;
      float sg = 1.f / (1.f + expf(-s));
      sg = fminf(fmaxf(sg, 1e-4f), 1.f - 1e-4f);
      sig[idx] = sg;
    }
  }
}

// ---------------- fallback: fp32 head2 ----------------
__global__ __launch_bounds__(256) void head2_kernel(
    const float* __restrict__ feat, const float* __restrict__ ws,
    const float* __restrict__ b1h, const float* __restrict__ b1o, const float* __restrict__ b1s,
    const float* __restrict__ w2h, const float* __restrict__ w2o, const float* __restrict__ w2s,
    const float* __restrict__ b2h, const float* __restrict__ b2o, const float* __restrict__ b2s,
    float* __restrict__ out)
{
  __shared__ float xs[32 * 10 * 34];
  const int tid = threadIdx.x;
  const int tx = tid & 31, ty = tid >> 5;
  const int x0 = blockIdx.x * 32, y0 = blockIdx.y * 8, bz = blockIdx.z;
  const int px = x0 + tx, py = y0 + ty;
  const float* w1r = ws + WS_W1R;

  #pragma unroll 1
  for (int br = 0; br < 3; ++br) {
    const float* wr = w1r + br * 147456;
    const float* b1 = br == 0 ? b1h : (br == 1 ? b1o : b1s);
    const float* w2 = br == 0 ? w2h : (br == 1 ? w2o : w2s);
    const int cout = (br == 0) ? 1 : 2;
    float acc0 = 0.f, acc1 = 0.f;
    #pragma unroll 1
    for (int c0 = 0; c0 < 256; c0 += 64) {
      float part[64];
      #pragma unroll
      for (int j = 0; j < 64; ++j) part[j] = 0.f;
      #pragma unroll 1
      for (int cc = 0; cc < 2; ++cc) {
        for (int i = tid; i < 32 * 10 * 34; i += 256) {
          int ci = i / 340; int rr = i - ci * 340; int ry = rr / 34; int rx = rr - ry * 34;
          int gy = y0 + ry - 1, gx = x0 + rx - 1;
          float v = 0.f;
          if ((unsigned)gy < 96u && (unsigned)gx < 320u)
            v = feat[((bz * 64 + cc * 32 + ci) * 96 + gy) * 320 + gx];
          xs[i] = v;
        }
        __syncthreads();
        #pragma unroll 1
        for (int ci = 0; ci < 32; ++ci) {
          const float* wp = wr + ((cc * 32 + ci) * 9) * 256 + c0;
          const float* xb = &xs[ci * 340 + ty * 34 + tx];
          #pragma unroll
          for (int k = 0; k < 9; ++k) {
            float xv = xb[(k / 3) * 34 + (k % 3)];
            const float* wk = wp + k * 256;
            #pragma unroll
            for (int j = 0; j < 64; ++j) part[j] = fmaf(wk[j], xv, part[j]);
          }
        }
        __syncthreads();
      }
      #pragma unroll
      for (int j = 0; j < 64; ++j) {
        float yv = part[j] + b1[c0 + j];
        yv = yv > 0.f ? yv : 0.f;
        acc0 = fmaf(w2[c0 + j], yv, acc0);
        if (cout > 1) acc1 = fmaf(w2[256 + c0 + j], yv, acc1);
      }
    }
    if (br == 0) {
      out[(bz * 96 + py) * 320 + px] = acc0 + b2h[0];
    } else if (br == 1) {
      out[OFF_O2 + ((bz * 2 + 0) * 96 + py) * 320 + px] = acc0 + b2o[0];
      out[OFF_O2 + ((bz * 2 + 1) * 96 + py) * 320 + px] = acc1 + b2o[1];
    } else {
      out[OFF_S2 + ((bz * 2 + 0) * 96 + py) * 320 + px] = acc0 + b2s[0];
      out[OFF_S2 + ((bz * 2 + 1) * 96 + py) * 320 + px] = acc1 + b2s[1];
    }
  }
}

// ---------------- NMS ----------------
__global__ void nms_sig_kernel(const float* __restrict__ out, float* __restrict__ sig)
{
  int i = blockIdx.x * 256 + threadIdx.x;
  if (i >= 8 * 30720) return;
  float s = 1.f / (1.f + expf(-out[i]));
  s = s < 1e-4f ? 1e-4f : s;
  float hi = 1.f - 1e-4f;
  sig[i] = s > hi ? hi : s;
}

__global__ void nms_max_kernel(const float* __restrict__ sig, float* __restrict__ keep)
{
  int i = blockIdx.x * 256 + threadIdx.x;
  if (i >= 8 * 30720) return;
  int b = i / 30720; int r = i - b * 30720; int y = r / 320; int x = r - y * 320;
  const float* sb = sig + b * 30720;
  float v = sb[y * 320 + x];
  float m = v;
  for (int dy = -1; dy <= 1; ++dy)
    for (int dx = -1; dx <= 1; ++dx) {
      int yy = y + dy, xx = x + dx;
      if (yy >= 0 && yy < 96 && xx >= 0 && xx < 320) m = fmaxf(m, sb[yy * 320 + xx]);
    }
  keep[i] = (m == v) ? v : 0.f;
}

// ---------------- per-batch top-50 (wave-shuffle argmax) + fused boxes ----------------
__global__ __launch_bounds__(256) void topk_kernel(float* ws, const float* __restrict__ out,
                                                   const float* __restrict__ coord_ranges,
                                                   const float* __restrict__ calibs)
{
  constexpr int CAP = 6144;
  __shared__ float cv[CAP];
  __shared__ int   cix[CAP];
  __shared__ int   cnt;
  __shared__ float wv_[4];
  __shared__ int   wi_[4];
  __shared__ int   wsl[4];
  int b = blockIdx.x, tid = threadIdx.x;
  int lane = tid & 63, wid = tid >> 6;
  if (tid == 0) cnt = 0;
  __syncthreads();
  const float* kb = ws + WS_KEEP + b * 30720;
  for (int i = tid; i < 30720; i += 256) {
    float v = kb[i];
    if (v > 0.f) {
      int pos = atomicAdd(&cnt, 1);
      if (pos < CAP) { cv[pos] = v; cix[pos] = i; }
    }
  }
  __syncthreads();
  int ncand = cnt < CAP ? cnt : CAP;
  int* inds = (int*)(ws + WS_INDS);
  for (int k = 0; k < 50; ++k) {
    float bv = -1.f; int bi = 0x7fffffff; int bs = -1;
    for (int i = tid; i < ncand; i += 256) {
      float v = cv[i]; int id = cix[i];
      if (v > bv || (v == bv && id < bi)) { bv = v; bi = id; bs = i; }
    }
    #pragma unroll
    for (int m = 1; m < 64; m <<= 1) {
      float ov = __shfl_xor(bv, m);
      int oi = __shfl_xor(bi, m);
      int os_ = __shfl_xor(bs, m);
      if (ov > bv || (ov == bv && oi < bi)) { bv = ov; bi = oi; bs = os_; }
    }
    if (lane == 0) { wv_[wid] = bv; wi_[wid] = bi; wsl[wid] = bs; }
    __syncthreads();
    if (tid == 0) {
      float fv = wv_[0]; int fi = wi_[0]; int fs = wsl[0];
      #pragma unroll
      for (int t = 1; t < 4; ++t) {
        if (wv_[t] > fv || (wv_[t] == fv && wi_[t] < fi)) { fv = wv_[t]; fi = wi_[t]; fs = wsl[t]; }
      }
      inds[b * 50 + k] = fi;
      if (fs >= 0) cv[fs] = -1.f;
    }
    __syncthreads();
  }
  // ---- fused boxes for this batch ----
  if (tid < 50) {
    int n = b * 50 + tid;
    int idx = inds[n];
    int iy = idx / 320, ix = idx - iy * 320;
    float o2x = out[OFF_O2 + ((b * 2 + 0) * 96 + iy) * 320 + ix];
    float o2y = out[OFF_O2 + ((b * 2 + 1) * 96 + iy) * 320 + ix];
    float sw  = out[OFF_S2 + ((b * 2 + 0) * 96 + iy) * 320 + ix];
    float sh  = out[OFF_S2 + ((b * 2 + 1) * 96 + iy) * 320 + ix];
    float cx = (float)ix + o2x, cy = (float)iy + o2y;
    float x1 = cx - sw * 0.5f, y1 = cy - sh * 0.5f, x2 = cx + sw * 0.5f, y2 = cy + sh * 0.5f;
    ws[WS_BOX + n * 4 + 0] = x1; ws[WS_BOX + n * 4 + 1] = y1;
    ws[WS_BOX + n * 4 + 2] = x2; ws[WS_BOX + n * 4 + 3] = y2;
    float cr00 = coord_ranges[b * 4 + 0], cr01 = coord_ranges[b * 4 + 1];
    float sx = coord_ranges[b * 4 + 2] - cr00, sy = coord_ranges[b * 4 + 3] - cr01;
    float x1r = x1 / 320.f * sx + cr00, y1r = y1 / 96.f * sy + cr01;
    float x2r = x2 / 320.f * sx + cr00, y2r = y2 / 96.f * sy + cr01;
    const float* cl = calibs + b * 12;
    float fu = cl[0], cu = cl[2], bxp = cl[3] / (-fu);
    float fv2 = cl[5], cvv = cl[6], byp = cl[7] / (-fv2);
    float p1x = (x1r - cu) / fu + bxp, p1y = (y1r - cvv) / fv2 + byp;
    float p2x = (x2r - cu) / fu + bxp, p2y = (y2r - cvv) / fv2 + byp;
    #pragma unroll
    for (int j = 0; j < 7; ++j) {
      float t = (float)j / 6.f;
      ws[WS_XS7 + n * 7 + j] = p1x + t * (p2x - p1x);
      ws[WS_YS7 + n * 7 + j] = p1y + t * (p2y - p1y);
    }
    ws[WS_FU + n] = fu;
    ws[WS_H2D + n] = fmaxf(y2r - y1r, 1.f);
  }
}

// ---------------- ROI-align + build roi_full (fp32) + fused fp16 A3 pack ----------------
__global__ __launch_bounds__(256) void roi_kernel(const float* __restrict__ feat, int fast3, float* ws)
{
  int n = blockIdx.x;
  int tid = threadIdx.x;
  __shared__ int   iy0[14], iy1[14], ix0[14], ix1[14];
  __shared__ float fy[14], fx[14], vy[14], vx[14];
  float bx1 = ws[WS_BOX + n * 4], by1 = ws[WS_BOX + n * 4 + 1];
  float bx2 = ws[WS_BOX + n * 4 + 2], by2 = ws[WS_BOX + n * 4 + 3];
  if (tid < 14) {
    float bh = fmaxf(by2 - by1, 1.f) / 7.f;
    float g = ((float)tid + 0.5f) * 0.5f;
    float c = by1 + g * bh;
    vy[tid] = (c >= -1.f && c <= 96.f) ? 1.f : 0.f;
    c = fminf(fmaxf(c, 0.f), 95.f);
    int i0 = (int)floorf(c);
    iy0[tid] = i0; iy1[tid] = (i0 + 1 < 95) ? i0 + 1 : 95;
    fy[tid] = c - (float)i0;
  } else if (tid < 28) {
    int t = tid - 14;
    float bw = fmaxf(bx2 - bx1, 1.f) / 7.f;
    float g = ((float)t + 0.5f) * 0.5f;
    float c = bx1 + g * bw;
    vx[t] = (c >= -1.f && c <= 320.f) ? 1.f : 0.f;
    c = fminf(fmaxf(c, 0.f), 319.f);
    int i0 = (int)floorf(c);
    ix0[t] = i0; ix1[t] = (i0 + 1 < 319) ? i0 + 1 : 319;
    fx[t] = c - (float)i0;
  }
  __syncthreads();
  int bsel = n / 50;
  const float* fbase = feat + bsel * 64 * 30720;
  float* rf = ws + WS_ROIF + n * 3381;
  for (int i = tid; i < 64 * 49; i += 256) {
    int c = i / 49, p = i - c * 49;
    int oy = p / 7, ox = p - oy * 7;
    const float* fb = fbase + c * 30720;
    float s = 0.f;
    #pragma unroll
    for (int sy2 = 0; sy2 < 2; ++sy2) {
      #pragma unroll
      for (int sx2 = 0; sx2 < 2; ++sx2) {
        int jy = oy * 2 + sy2, jx = ox * 2 + sx2;
        const float* r0 = fb + iy0[jy] * 320;
        const float* r1 = fb + iy1[jy] * 320;
        float gy = fy[jy], gx = fx[jx];
        float v00 = r0[ix0[jx]], v01 = r0[ix1[jx]], v10 = r1[ix0[jx]], v11 = r1[ix1[jx]];
        float v = v00 * (1.f - gy) * (1.f - gx) + v01 * (1.f - gy) * gx
                + v10 * gy * (1.f - gx) + v11 * gy * gx;
        s += v * vy[jy] * vx[jx];
      }
    }
    rf[c * 49 + p] = s * 0.25f;
  }
  if (tid < 5 * 49) {
    int ch = tid / 49, p = tid - ch * 49;
    int oy = p / 7, ox = p - oy * 7;
    float v;
    if (ch == 0) v = ws[WS_XS7 + n * 7 + ox];
    else if (ch == 1) v = ws[WS_YS7 + n * 7 + oy];
    else if (ch == 2) v = 1.f;
    else v = 0.f;
    rf[(64 + ch) * 49 + p] = v;
  }
  if (fast3) {
    __syncthreads();
    unsigned short* a3 = (unsigned short*)(ws + WS_A3) + (size_t)n * 7776;
    for (int t = 0; t < 31; ++t) {
      int i = t * 256 + tid;
      if (i < 7776) {
        int pr = i / 96, ch = i - pr * 96;
        int py = pr / 9, px = pr - py * 9;
        float v = 0.f;
        if (py >= 1 && py <= 7 && px >= 1 && px <= 7 && ch < 69)
          v = rf[ch * 49 + (py - 1) * 7 + (px - 1)];
        a3[i] = __builtin_bit_cast(unsigned short, (_Float16)v);
      }
    }
  }
}

// ---------------- fast3: head3 MFMA (1 roi x 1 branch per block) + setprio ----------------
__global__ __launch_bounds__(256, 2) void head3m_kernel(
    float* __restrict__ ws,
    const float* __restrict__ b1d, const float* __restrict__ b1o3, const float* __restrict__ b1s3, const float* __restrict__ b1hd,
    const float* __restrict__ w2d, const float* __restrict__ w2o3, const float* __restrict__ w2s3, const float* __restrict__ w2hd,
    const float* __restrict__ b2d, const float* __restrict__ b2o3, const float* __restrict__ b2s3, const float* __restrict__ b2hd,
    float* __restrict__ out)
{
  __shared__ unsigned char A[81 * 104 * 2];
  __shared__ float ym[256];
  const int tid = threadIdx.x;
  const int l = tid & 63, w = tid >> 6;
  const int l15 = l & 15, lg = l >> 4;
  const int n = blockIdx.x;
  const int br = blockIdx.y;
  const unsigned short* a3 = (const unsigned short*)(ws + WS_A3) + (size_t)n * 7776;
  const _Float16* wp3 = (const _Float16*)(ws + WS_WPACK3);

  #pragma unroll
  for (int t = 0; t < 4; ++t) {
    int u = t * 256 + tid;
    if (u < 972) {
      int row = u / 12, cu = u - row * 12;
      u32x4 v = *(const u32x4*)(a3 + u * 8);
      *(u32x4*)(A + (row * 104 + cu * 8) * 2) = v;
    }
  }
  __syncthreads();

  int aB[4];
  #pragma unroll
  for (int pf = 0; pf < 4; ++pf) {
    int p = pf * 16 + l15;
    int rb = (p < 49) ? ((p / 7) * 9 + (p % 7)) : 0;
    aB[pf] = rb * 208 + lg * 16;
  }

  const float* b1 = br == 0 ? b1d : (br == 1 ? b1o3 : (br == 2 ? b1s3 : b1hd));
  const float* w2 = br == 0 ? w2d : (br == 1 ? w2o3 : (br == 2 ? w2s3 : w2hd));
  const float* b2 = br == 0 ? b2d : (br == 1 ? b2o3 : (br == 2 ? b2s3 : b2hd));
  const int cout = br == 0 ? 2 : (br == 1 ? 2 : (br == 2 ? 4 : 24));

  f32x4 acc[4][4];
  #pragma unroll
  for (int i = 0; i < 4; ++i)
    #pragma unroll
    for (int j = 0; j < 4; ++j) acc[i][j] = (f32x4)(0.f);

  const _Float16* wB3 = wp3 + (((long long)(br * 27) * 16 + w * 4) * 4 + lg) * 128 + l15 * 8;

  #pragma unroll
  for (int s = 0; s < 27; ++s) {
    const int tap = s / 3, cc = s - tap * 3;
    const int ky = tap / 3, kx = tap - ky * 3;
    const int stepOff = (ky * 9 + kx) * 208 + cc * 64;
    f16x8 af[4], bf[4];
    #pragma unroll
    for (int pf = 0; pf < 4; ++pf)
      af[pf] = *(const f16x8*)(A + aB[pf] + stepOff);
    #pragma unroll
    for (int nf = 0; nf < 4; ++nf)
      bf[nf] = *(const f16x8*)(wB3 + s * 8192 + nf * 512);
    __builtin_amdgcn_s_setprio(1);
    #pragma unroll
    for (int pf = 0; pf < 4; ++pf)
      #pragma unroll
      for (int nf = 0; nf < 4; ++nf)
        acc[pf][nf] = __builtin_amdgcn_mfma_f32_16x16x32_f16(af[pf], bf[nf], acc[pf][nf], 0, 0, 0);
    __builtin_amdgcn_s_setprio(0);
  }

  #pragma unroll
  for (int nf = 0; nf < 4; ++nf) {
    int nn = w * 64 + nf * 16 + l15;
    float b1n = b1[nn];
    float scn = ws[WS_BNSC + br * 256 + nn];
    float shn = ws[WS_BNSH + br * 256 + nn];
    float local = 0.f;
    #pragma unroll
    for (int pf = 0; pf < 4; ++pf) {
      #pragma unroll
      for (int rr = 0; rr < 4; ++rr) {
        int p = pf * 16 + lg * 4 + rr;
        float yv = (acc[pf][nf][rr] + b1n) * scn + shn;
        yv = yv > 0.f ? yv : 0.f;
        local += (p < 49) ? yv : 0.f;
      }
    }
    local += __shfl_xor(local, 16);
    local += __shfl_xor(local, 32);
    if (lg == 0) ym[nn] = local;
  }
  __syncthreads();
  for (int o = w; o < cout; o += 4) {
    float p = 0.f;
    #pragma unroll
    for (int t = 0; t < 4; ++t) p = fmaf(w2[o * 256 + t * 64 + l], ym[t * 64 + l], p);
    p *= (1.f / 49.f);
    #pragma unroll
    for (int off = 32; off > 0; off >>= 1) p += __shfl_down(p, off);
    if (l == 0) {
      float v = p + b2[o];
      if (br == 0) ws[WS_DNO + n * 2 + o] = v;
      else if (br == 1) out[OFF_O3D + n * 2 + o] = v;
      else if (br == 2) { if (o < 3) out[OFF_S3D + n * 3 + o] = v; else out[OFF_H3D + n] = v; }
      else out[OFF_HEAD + n * 24 + o] = v;
    }
  }
}

// ---------------- fallback: fp32 head3 ----------------
__global__ __launch_bounds__(256) void head3_kernel(
    float* ws,
    const float* __restrict__ b1d, const float* __restrict__ b1o3, const float* __restrict__ b1s3, const float* __restrict__ b1hd,
    const float* __restrict__ w2d, const float* __restrict__ w2o3, const float* __restrict__ w2s3, const float* __restrict__ w2hd,
    const float* __restrict__ b2d, const float* __restrict__ b2o3, const float* __restrict__ b2s3, const float* __restrict__ b2hd,
    float* __restrict__ out)
{
  int n = blockIdx.x, br = blockIdx.y;
  int c = threadIdx.x;
  __shared__ float ym[256];
  const float* wt = ws + WS_W1T + br * 158976;
  const float* b1 = br == 0 ? b1d : (br == 1 ? b1o3 : (br == 2 ? b1s3 : b1hd));
  const float* w2 = br == 0 ? w2d : (br == 1 ? w2o3 : (br == 2 ? w2s3 : w2hd));
  const float* b2 = br == 0 ? b2d : (br == 1 ? b2o3 : (br == 2 ? b2s3 : b2hd));
  const int cout = br == 0 ? 2 : (br == 1 ? 2 : (br == 2 ? 4 : 24));
  const float* xin0 = ws + WS_ROIF + n * 3381;

  float acc[49];
  #pragma unroll
  for (int i = 0; i < 49; ++i) acc[i] = 0.f;

  #pragma unroll 1
  for (int ci = 0; ci < 69; ++ci) {
    float wv[9];
    #pragma unroll
    for (int k = 0; k < 9; ++k) wv[k] = wt[(ci * 9 + k) * 256 + c];
    const float* xin = xin0 + ci * 49;
    #pragma unroll
    for (int y = 0; y < 7; ++y) {
      float xr[9];
      xr[0] = 0.f; xr[8] = 0.f;
      #pragma unroll
      for (int q = 0; q < 7; ++q) xr[q + 1] = xin[y * 7 + q];
      #pragma unroll
      for (int ky = 0; ky < 3; ++ky) {
        int pyy = y + 1 - ky;
        if (pyy >= 0 && pyy < 7) {
          #pragma unroll
          for (int kx = 0; kx < 3; ++kx) {
            float w = wv[ky * 3 + kx];
            #pragma unroll
            for (int pxx = 0; pxx < 7; ++pxx)
              acc[pyy * 7 + pxx] = fmaf(w, xr[pxx + kx], acc[pyy * 7 + pxx]);
          }
        }
      }
    }
  }
  float b1c = b1[c];
  float sc = ws[WS_BNSC + br * 256 + c];
  float sh = ws[WS_BNSH + br * 256 + c];
  float sum = 0.f;
  #pragma unroll
  for (int i = 0; i < 49; ++i) {
    float yv = (acc[i] + b1c) * sc + sh;
    sum += yv > 0.f ? yv : 0.f;
  }
  ym[c] = sum / 49.f;
  __syncthreads();
  int lane = c & 63, wid = c >> 6;
  for (int o = wid; o < cout; o += 4) {
    float p = 0.f;
    #pragma unroll
    for (int t = 0; t < 4; ++t) p = fmaf(w2[o * 256 + t * 64 + lane], ym[t * 64 + lane], p);
    #pragma unroll
    for (int off = 32; off > 0; off >>= 1) p += __shfl_down(p, off);
    if (lane == 0) {
      float v = p + b2[o];
      if (br == 0) ws[WS_DNO + n * 2 + o] = v;
      else if (br == 1) out[OFF_O3D + n * 2 + o] = v;
      else if (br == 2) { if (o < 3) out[OFF_S3D + n * 3 + o] = v; else out[OFF_H3D + n] = v; }
      else out[OFF_HEAD + n * 24 + o] = v;
    }
  }
}

// ---------------- depth epilogue ----------------
__global__ void depth_kernel(const float* ws, const float* __restrict__ mean_size, float* __restrict__ out)
{
  int n = blockIdx.x * 256 + threadIdx.x;
  if (n >= 400) return;
  float h3d = out[OFF_H3D + n];
  float s30 = out[OFF_S3D + n * 3];
  float size0 = mean_size[0] + s30;
  float f = ws[WS_FU + n], h = ws[WS_H2D + n];
  float dgeo = size0 / h * f;
  float geo = h3d + 2.f * (logf(f) - logf(h));
  float a = ws[WS_DNO + n * 2 + 1];
  float mx = fmaxf(a, geo);
  float nls = mx + logf(expf(a - mx) + expf(geo - mx));
  float sg = 1.f / (1.f + expf(-ws[WS_DNO + n * 2]));
  out[OFF_DEPTH + n * 2] = 1.f / (sg + 1e-6f) - 1.f + dgeo;
  out[OFF_DEPTH + n * 2 + 1] = nls;
}

// ---------------- launch ----------------
extern "C" void kernel_launch(void* const* d_in, const int* in_sizes, int n_in,
                              void* d_out, int out_size, void* d_ws, size_t ws_size,
                              hipStream_t stream)
{
  const float* feat         = (const float*)d_in[0];
  const float* coord_ranges = (const float*)d_in[1];
  const float* calibs       = (const float*)d_in[2];
  const float* mean_size    = (const float*)d_in[3];
  const float* hm_w1 = (const float*)d_in[4];
  const float* hm_b1 = (const float*)d_in[5];
  const float* hm_w2 = (const float*)d_in[6];
  const float* hm_b2 = (const float*)d_in[7];
  const float* o2_w1 = (const float*)d_in[8];
  const float* o2_b1 = (const float*)d_in[9];
  const float* o2_w2 = (const float*)d_in[10];
  const float* o2_b2 = (const float*)d_in[11];
  const float* s2_w1 = (const float*)d_in[12];
  const float* s2_b1 = (const float*)d_in[13];
  const float* s2_w2 = (const float*)d_in[14];
  const float* s2_b2 = (const float*)d_in[15];
  const float* dep_w1 = (const float*)d_in[16];
  const float* dep_b1 = (const float*)d_in[17];
  const float* dep_g  = (const float*)d_in[18];
  const float* dep_be = (const float*)d_in[19];
  const float* dep_m  = (const float*)d_in[20];
  const float* dep_v  = (const float*)d_in[21];
  const float* dep_w2 = (const float*)d_in[22];
  const float* dep_b2 = (const float*)d_in[23];
  const float* o3_w1 = (const float*)d_in[24];
  const float* o3_b1 = (const float*)d_in[25];
  const float* o3_g  = (const float*)d_in[26];
  const float* o3_be = (const float*)d_in[27];
  const float* o3_m  = (const float*)d_in[28];
  const float* o3_v  = (const float*)d_in[29];
  const float* o3_w2 = (const float*)d_in[30];
  const float* o3_b2 = (const float*)d_in[31];
  const float* s3_w1 = (const float*)d_in[32];
  const float* s3_b1 = (const float*)d_in[33];
  const float* s3_g  = (const float*)d_in[34];
  const float* s3_be = (const float*)d_in[35];
  const float* s3_m  = (const float*)d_in[36];
  const float* s3_v  = (const float*)d_in[37];
  const float* s3_w2 = (const float*)d_in[38];
  const float* s3_b2 = (const float*)d_in[39];
  const float* hd_w1 = (const float*)d_in[40];
  const float* hd_b1 = (const float*)d_in[41];
  const float* hd_g  = (const float*)d_in[42];
  const float* hd_be = (const float*)d_in[43];
  const float* hd_m  = (const float*)d_in[44];
  const float* hd_v  = (const float*)d_in[45];
  const float* hd_w2 = (const float*)d_in[46];
  const float* hd_b2 = (const float*)d_in[47];

  float* out = (float*)d_out;
  float* ws  = (float*)d_ws;
  bool fast  = (long long)ws_size >= FAST_REQ_BYTES;
  bool fast3 = (long long)ws_size >= FAST3_REQ_BYTES;

  if (fast) {
    int nprep = 7820 + (fast3 ? 3456 : 0);
    prep_kernel<<<dim3(nprep), 256, 0, stream>>>(feat,
        hm_w1, o2_w1, s2_w1, dep_w1, o3_w1, s3_w1, hd_w1,
        dep_g, dep_be, dep_m, dep_v, o3_g, o3_be, o3_m, o3_v,
        s3_g, s3_be, s3_m, s3_v, hd_g, hd_be, hd_m, hd_v, ws);
    if (!fast3) {
      repack_kernel<<<dim3((3 * 147456 + 4 * 158976 + 1024 + 255) / 256), 256, 0, stream>>>(
          hm_w1, o2_w1, s2_w1, dep_w1, o3_w1, s3_w1, hd_w1,
          dep_g, dep_be, dep_m, dep_v, o3_g, o3_be, o3_m, o3_v,
          s3_g, s3_be, s3_m, s3_v, hd_g, hd_be, hd_m, hd_v,
          1, 0, ws);
    }
    head2f_kernel<<<dim3(3840), 256, 0, stream>>>(ws,
        o2_b1, s2_b1, hm_b1, o2_w2, s2_w2, hm_w2, o2_b2, s2_b2, hm_b2, out, ws + WS_SIG);
  } else {
    repack_kernel<<<dim3((3 * 147456 + 4 * 158976 + 1024 + 255) / 256), 256, 0, stream>>>(
        hm_w1, o2_w1, s2_w1, dep_w1, o3_w1, s3_w1, hd_w1,
        dep_g, dep_be, dep_m, dep_v, o3_g, o3_be, o3_m, o3_v,
        s3_g, s3_be, s3_m, s3_v, hd_g, hd_be, hd_m, hd_v,
        0, 0, ws);
    head2_kernel<<<dim3(10, 12, 8), 256, 0, stream>>>(feat, ws,
        hm_b1, o2_b1, s2_b1, hm_w2, o2_w2, s2_w2, hm_b2, o2_b2, s2_b2, out);
    nms_sig_kernel<<<dim3(960), 256, 0, stream>>>(out, ws + WS_SIG);
  }

  nms_max_kernel<<<dim3(960), 256, 0, stream>>>(ws + WS_SIG, ws + WS_KEEP);
  topk_kernel<<<dim3(8), 256, 0, stream>>>(ws, out, coord_ranges, calibs);
  roi_kernel<<<dim3(400), 256, 0, stream>>>(feat, fast3 ? 1 : 0, ws);
  if (fast3) {
    head3m_kernel<<<dim3(400, 4), 256, 0, stream>>>(ws,
        dep_b1, o3_b1, s3_b1, hd_b1, dep_w2, o3_w2, s3_w2, hd_w2,
        dep_b2, o3_b2, s3_b2, hd_b2, out);
  } else {
    head3_kernel<<<dim3(400, 4), 256, 0, stream>>>(ws,
        dep_b1, o3_b1, s3_b1, hd_b1, dep_w2, o3_w2, s3_w2, hd_w2,
        dep_b2, o3_b2, s3_b2, hd_b2, out);
  }
  depth_kernel<<<dim3(2), 256, 0, stream>>>(ws, mean_size, out);
}